// Round 4
// baseline (354.092 us; speedup 1.0000x reference)
//
#include <hip/hip_runtime.h>
#include <hip/hip_bf16.h>

#define S_LEN 2048
#define DK 128
#define DV 128
#define BM 64     // Q rows per block (4 waves, kv/d split across waves)
#define BN 64     // KV rows per tile
#define NT 32     // KV tiles per batch
#define LDP 72    // LDS P row stride (bf16)
#define TILE_B 16384                        // bytes per staged tile (64x128 bf16)
#define VWS_OFF ((size_t)16 * NT * TILE_B)  // 8.39 MB
#define WS_NEED ((size_t)2 * 16 * NT * TILE_B)
// split-KV partial buffers
#define PART_OFF WS_NEED                              // h=1 acc partial, 16.78 MB
#define PART_B   ((size_t)16 * S_LEN * DV * 4)
#define L0_OFF   (PART_OFF + PART_B)                  // l partials, 128 KB each
#define L1_OFF   (L0_OFF + (size_t)16 * S_LEN * 4)
#define WS_NEED_SPLIT (L1_OFF + (size_t)16 * S_LEN * 4)

typedef __attribute__((ext_vector_type(8))) short s16x8;
typedef __attribute__((ext_vector_type(4))) short s16x4;
typedef __attribute__((ext_vector_type(8))) __bf16 bf16x8;
typedef __attribute__((ext_vector_type(4))) float f32x4;

__device__ __forceinline__ short f2bf(float f) {
  unsigned u = __builtin_bit_cast(unsigned, f);
  u += 0x7FFFu + ((u >> 16) & 1u);
  return (short)(u >> 16);
}
__device__ __forceinline__ bf16x8 lds8(const short* p) {
  return __builtin_bit_cast(bf16x8, *(const s16x8*)p);
}
__device__ __forceinline__ bf16x8 gload8v(const char* p) {
  return __builtin_bit_cast(bf16x8, *(const s16x8*)p);
}
// packed f32x2 -> bf16x2 (RNE): low = a, high = b
__device__ __forceinline__ unsigned cvtpk(float a, float b) {
  unsigned r;
  asm("v_cvt_pk_bf16_f32 %0, %1, %2" : "=v"(r) : "v"(a), "v"(b));
  return r;
}

// ---------------------------------------------------------------------------
// Pass 1: convert K -> bf16 and V -> bf16-transposed, tile-major, chunks
// pre-permuted in the XOR-swizzled order (addresses fold the same XOR).
//   K tile:  chunk(r,cix) at position r*16 + (cix ^ (r&7))
//   Vt tile: chunk(d,cix) at position d*8 + (cix ^ (d&7))
// ---------------------------------------------------------------------------
__global__ __launch_bounds__(256)
void fa_convert(const float* __restrict__ K, const float* __restrict__ V,
                char* __restrict__ ws) {
  __shared__ short tlds[BN * 130];  // 16640 B, V path only
  const int bid = blockIdx.x;
  const int tid = threadIdx.x;
  if (bid < 512) {  // K: bid = b*32 + kt
    const int b = bid >> 5, kt = bid & 31;
    const float* kb = K + (size_t)(b * S_LEN + kt * BN) * DK;
    short* out = (short*)(ws + (size_t)bid * TILE_B);
#pragma unroll
    for (int it = 0; it < 4; ++it) {
      int o = it * 256 + tid;
      int r = o >> 4, cix = o & 15;
      const float* src = kb + r * DK + cix * 8;
      float4 x = *(const float4*)src;
      float4 y = *(const float4*)(src + 4);
      s16x8 f;
      f[0] = f2bf(x.x); f[1] = f2bf(x.y); f[2] = f2bf(x.z); f[3] = f2bf(x.w);
      f[4] = f2bf(y.x); f[5] = f2bf(y.y); f[6] = f2bf(y.z); f[7] = f2bf(y.w);
      int pos = r * 16 + (cix ^ (r & 7));
      *(s16x8*)(out + pos * 8) = f;
    }
  } else {  // V transpose via LDS: vb = b*32 + kt
    const int vb = bid - 512;
    const float* vbase = V + (size_t)((vb >> 5) * S_LEN + (vb & 31) * BN) * DV;
    short* out = (short*)(ws + VWS_OFF + (size_t)vb * TILE_B);
#pragma unroll
    for (int i = 0; i < 8; ++i) {
      int idx = i * 256 + tid;        // float4 index, 2048 total
      int r = idx >> 5, c4 = idx & 31;
      float4 x = *(const float4*)(vbase + r * DV + c4 * 4);
      unsigned lo = ((unsigned)(unsigned short)f2bf(x.y) << 16) |
                    (unsigned short)f2bf(x.x);
      unsigned hi = ((unsigned)(unsigned short)f2bf(x.w) << 16) |
                    (unsigned short)f2bf(x.z);
      *(unsigned*)&tlds[r * 130 + c4 * 4] = lo;
      *(unsigned*)&tlds[r * 130 + c4 * 4 + 2] = hi;
    }
    __syncthreads();
#pragma unroll
    for (int i = 0; i < 2; ++i) {
      int idx = i * 256 + tid;        // pair index, 512 total
      int dp = idx >> 3, cix = idx & 7;
      int d = dp * 2;
      s16x8 f0, f1;
#pragma unroll
      for (int j = 0; j < 8; ++j) {
        int r = cix * 8 + j;
        unsigned two = *(const unsigned*)&tlds[r * 130 + d];
        f0[j] = (short)(two & 0xFFFFu);
        f1[j] = (short)(two >> 16);
      }
      int p0 = d * 8 + (cix ^ (d & 7));
      int p1 = (d + 1) * 8 + (cix ^ ((d + 1) & 7));
      *(s16x8*)(out + p0 * 8) = f0;
      *(s16x8*)(out + p1 * 8) = f1;
    }
  }
}

// ---------------------------------------------------------------------------
// Pass 2 (split-KV): 1024 blocks, block = (batch, q-tile t, half h).
// h=0 covers kv tiles [0,(t+2)/2), h=1 covers [(t+2)/2, t+1) -> max 16
// steps/block (was 32) and 4 blocks/CU co-resident (launch_bounds(256,4)
// caps VGPR at 128 -> 16 waves/CU). Fixed-m softmax (m=16) makes partials
// combine by PLAIN ADDITION: h=0 writes unnormalized acc to Out, h=1 to ws;
// fa_combine adds and normalizes. Deterministic, no atomics.
// Ping-pong barrier schedule + direct-L2 frag reads as in R3.
// XCD remap: 2 batches per XCD; heaviest (t=31) blocks dispatch first.
// ---------------------------------------------------------------------------
__global__ __launch_bounds__(256, 4)
void fa_main_split(const float* __restrict__ Q, char* __restrict__ ws,
                   float* __restrict__ Out) {
  __shared__ __align__(16) short lds_p0[64 * LDP];
  __shared__ __align__(16) short lds_p1[64 * LDP];
  __shared__ float lds_l[4][64];

  const int bid = blockIdx.x;           // [0,1024)
  const int x = bid & 7, j = bid >> 3;  // j in [0,128)
  const int u = j >> 1;                 // [0,64): (t,h), heavy-first
  const int b = x + 8 * (j & 1);
  const int t = 31 - (u >> 1);
  const int h = u & 1;
  const int lo = h ? ((t + 2) >> 1) : 0;
  const int hi = h ? (t + 1) : ((t + 2) >> 1);
  const int n  = hi - lo;

  const int q0  = t * BM;
  const int tid = threadIdx.x;
  const int wv  = tid >> 6, ln = tid & 63;
  const int c   = ln & 15, qd = ln >> 4;
  const int s3  = c & 7;
  const float scale2 = 0.12751741f;      // log2(e)/sqrt(128), folded into Q

  // Q frags for ALL 64 q rows: qf[qt][ks] = Q[q0+qt*16+c][ks*32+qd*8 ..+8]*scale2
  bf16x8 qf[4][4];
#pragma unroll
  for (int qt = 0; qt < 4; ++qt) {
    const float* qrow = Q + (size_t)(b * S_LEN + q0 + qt * 16 + c) * DK + qd * 8;
#pragma unroll
    for (int ks = 0; ks < 4; ++ks) {
      float4 xv = *(const float4*)(qrow + ks * 32);
      float4 yv = *(const float4*)(qrow + ks * 32 + 4);
      s16x8 f;
      f[0] = f2bf(xv.x * scale2); f[1] = f2bf(xv.y * scale2);
      f[2] = f2bf(xv.z * scale2); f[3] = f2bf(xv.w * scale2);
      f[4] = f2bf(yv.x * scale2); f[5] = f2bf(yv.y * scale2);
      f[6] = f2bf(yv.z * scale2); f[7] = f2bf(yv.w * scale2);
      qf[qt][ks] = __builtin_bit_cast(bf16x8, f);
    }
  }

  // step-invariant global frag byte offsets within a tile
  int kgo[4], vgo[2][2];
#pragma unroll
  for (int ks = 0; ks < 4; ++ks)
    kgo[ks] = ((wv * 16 + c) * 16 + ((qd + 4 * ks) ^ s3)) * 16;
#pragma unroll
  for (int dt = 0; dt < 2; ++dt)
#pragma unroll
    for (int kvs = 0; kvs < 2; ++kvs)
      vgo[dt][kvs] = ((wv * 32 + dt * 16 + c) * 8 + ((qd + 4 * kvs) ^ s3)) * 16;

  const char* kbase = ws + (size_t)(b * NT) * TILE_B;
  const char* vbase = ws + VWS_OFF + (size_t)(b * NT) * TILE_B;

  f32x4 oacc[2][4];
#pragma unroll
  for (int dt = 0; dt < 2; ++dt)
#pragma unroll
    for (int qt = 0; qt < 4; ++qt) oacc[dt][qt] = f32x4{0.f, 0.f, 0.f, 0.f};
  float l4[4] = {0.f, 0.f, 0.f, 0.f};
  f32x4 st[4];

  auto loadK = [&](bf16x8 (&dst)[4], int kt_) {
    const char* kb_ = kbase + (size_t)kt_ * TILE_B;
#pragma unroll
    for (int ks = 0; ks < 4; ++ks) dst[ks] = gload8v(kb_ + kgo[ks]);
  };
  auto loadV = [&](bf16x8 (&dst)[2][2], int kt_) {
    const char* vb_ = vbase + (size_t)kt_ * TILE_B;
#pragma unroll
    for (int dt = 0; dt < 2; ++dt)
#pragma unroll
      for (int kvs = 0; kvs < 2; ++kvs) dst[dt][kvs] = gload8v(vb_ + vgo[dt][kvs]);
  };
  auto qk = [&](bf16x8 (&kfr)[4]) {
    __builtin_amdgcn_s_setprio(1);
#pragma unroll
    for (int qt = 0; qt < 4; ++qt) {
      f32x4 acc = f32x4{0.f, 0.f, 0.f, 0.f};
#pragma unroll
      for (int ks = 0; ks < 4; ++ks)
        acc = __builtin_amdgcn_mfma_f32_16x16x32_bf16(kfr[ks], qf[qt][ks], acc, 0, 0, 0);
      st[qt] = acc;
    }
    __builtin_amdgcn_s_setprio(0);
  };
  auto smax = [&](short* pbuf, bool mask) {
    if (mask) {
#pragma unroll
      for (int qt = 0; qt < 4; ++qt)
#pragma unroll
        for (int r = 0; r < 4; ++r)
          if (wv * 16 + qd * 4 + r > qt * 16 + c) st[qt][r] = -1e30f;
    }
#pragma unroll
    for (int qt = 0; qt < 4; ++qt) {
      float p0 = __builtin_amdgcn_exp2f(st[qt][0] - 16.0f);
      float p1 = __builtin_amdgcn_exp2f(st[qt][1] - 16.0f);
      float p2 = __builtin_amdgcn_exp2f(st[qt][2] - 16.0f);
      float p3 = __builtin_amdgcn_exp2f(st[qt][3] - 16.0f);
      l4[qt] += (p0 + p1) + (p2 + p3);
      uint2 w; w.x = cvtpk(p0, p1); w.y = cvtpk(p2, p3);
      *(uint2*)&pbuf[(qt * 16 + c) * LDP + wv * 16 + qd * 4] = w;
    }
  };
  auto pv = [&](bf16x8 (&vfr)[2][2], const short* pbuf) {
#pragma unroll
    for (int kvs = 0; kvs < 2; ++kvs) {
      bf16x8 pf[4];
#pragma unroll
      for (int qt = 0; qt < 4; ++qt)
        pf[qt] = lds8(&pbuf[(qt * 16 + c) * LDP + kvs * 32 + qd * 8]);
      __builtin_amdgcn_s_setprio(1);
#pragma unroll
      for (int dt = 0; dt < 2; ++dt)
#pragma unroll
        for (int qt = 0; qt < 4; ++qt)
          oacc[dt][qt] = __builtin_amdgcn_mfma_f32_16x16x32_bf16(
              vfr[dt][kvs], pf[qt], oacc[dt][qt], 0, 0, 0);
      __builtin_amdgcn_s_setprio(0);
    }
  };
  auto bar = [&]() {
    asm volatile("s_waitcnt lgkmcnt(0)" ::: "memory");
    __builtin_amdgcn_s_barrier();
    asm volatile("" ::: "memory");
  };

  // named double buffers (no runtime indexing -> stays in registers)
  bf16x8 kf0[4], kf1[4], vf0[2][2], vf1[2][2];

  if (n > 0) {
    loadK(kf0, lo); loadV(vf0, lo);
    if (n >= 2) { loadK(kf1, lo + 1); loadV(vf1, lo + 1); }
    qk(kf0);
    smax(lds_p0, lo == t);
    bar();
    // invariant at loop top (i even): P(lo+i) in pb0, kf1/vf1 hold tile lo+i+1
    int i = 0;
    while (i + 1 < n) {
      qk(kf1);
      if (i + 2 < n) loadK(kf0, lo + i + 2);
      pv(vf0, lds_p0);
      if (i + 2 < n) loadV(vf0, lo + i + 2);
      smax(lds_p1, lo + i + 1 == t);
      bar();
      ++i;
      if (i + 1 >= n) break;
      qk(kf0);
      if (i + 2 < n) loadK(kf1, lo + i + 2);
      pv(vf1, lds_p1);
      if (i + 2 < n) loadV(vf1, lo + i + 2);
      smax(lds_p0, lo + i + 1 == t);
      bar();
      ++i;
    }
    if (i & 1) pv(vf1, lds_p1);
    else       pv(vf0, lds_p0);
  }

  // l reduction: over qd lanes (shfl) then over waves (LDS)
#pragma unroll
  for (int qt = 0; qt < 4; ++qt) {
    l4[qt] += __shfl_xor(l4[qt], 16);
    l4[qt] += __shfl_xor(l4[qt], 32);
  }
  if (qd == 0) {
#pragma unroll
    for (int qt = 0; qt < 4; ++qt) lds_l[wv][qt * 16 + c] = l4[qt];
  }
  __syncthreads();
  float lt[4];
#pragma unroll
  for (int qt = 0; qt < 4; ++qt)
    lt[qt] = lds_l[0][qt * 16 + c] + lds_l[1][qt * 16 + c] +
             lds_l[2][qt * 16 + c] + lds_l[3][qt * 16 + c];

  // epilogue: store UNNORMALIZED partial acc + l; combine kernel finishes
  float* obase = h ? (float*)(ws + PART_OFF) : Out;
  float* lbase = (float*)(ws + (h ? L1_OFF : L0_OFF)) + (size_t)b * S_LEN;
  if (wv == 0 && qd == 0) {
#pragma unroll
    for (int qt = 0; qt < 4; ++qt) lbase[q0 + qt * 16 + c] = lt[qt];
  }
#pragma unroll
  for (int qt = 0; qt < 4; ++qt) {
    float* ob = obase + (size_t)(b * S_LEN + q0 + qt * 16 + c) * DV + wv * 32;
#pragma unroll
    for (int dt = 0; dt < 2; ++dt)
      *(f32x4*)(ob + dt * 16 + qd * 4) = oacc[dt][qt];
  }
}

// Combine: Out = (Out + P1) / (l0 + l1). 2048 blocks x 256 threads x 8 floats.
__global__ __launch_bounds__(256)
void fa_combine(float* __restrict__ Out, const char* __restrict__ ws) {
  const float* P1 = (const float*)(ws + PART_OFF);
  const float* L0 = (const float*)(ws + L0_OFF);
  const float* L1 = (const float*)(ws + L1_OFF);
  const int base = (blockIdx.x * 256 + threadIdx.x) * 8;
  const int q = base >> 7;  // global row in [0, 16*2048)
  float inv = 1.0f / (L0[q] + L1[q]);
  f32x4 a0 = *(const f32x4*)(Out + base);
  f32x4 a1 = *(const f32x4*)(P1 + base);
  f32x4 b0 = *(const f32x4*)(Out + base + 4);
  f32x4 b1 = *(const f32x4*)(P1 + base + 4);
  *(f32x4*)(Out + base)     = (a0 + a1) * inv;
  *(f32x4*)(Out + base + 4) = (b0 + b1) * inv;
}

// ---------------------------------------------------------------------------
// Mid-tier (ws fits KV only): R3's verified ping-pong kernel, 512 blocks.
// ---------------------------------------------------------------------------
__global__ __launch_bounds__(256, 2)
void fa_main_pair(const float* __restrict__ Q, const char* __restrict__ ws,
                  float* __restrict__ Out) {
  __shared__ __align__(16) short lds_p0[64 * LDP];
  __shared__ __align__(16) short lds_p1[64 * LDP];
  __shared__ float lds_l[4][64];

  const int bid = blockIdx.x;
  const int x = bid & 7, j = bid >> 3;
  int b, t;
  if (j < 32) { b = x + 8 * (j & 1); t = 16 + (j >> 1); }
  else        { int jj = j - 32; b = x + 8 * (jj & 1); t = 15 - (jj >> 1); }
  const int q0  = t * BM;
  const int tid = threadIdx.x;
  const int wv  = tid >> 6, ln = tid & 63;
  const int c   = ln & 15, qd = ln >> 4;
  const int s3  = c & 7;
  const float scale2 = 0.12751741f;

  bf16x8 qf[4][4];
#pragma unroll
  for (int qt = 0; qt < 4; ++qt) {
    const float* qrow = Q + (size_t)(b * S_LEN + q0 + qt * 16 + c) * DK + qd * 8;
#pragma unroll
    for (int ks = 0; ks < 4; ++ks) {
      float4 xv = *(const float4*)(qrow + ks * 32);
      float4 yv = *(const float4*)(qrow + ks * 32 + 4);
      s16x8 f;
      f[0] = f2bf(xv.x * scale2); f[1] = f2bf(xv.y * scale2);
      f[2] = f2bf(xv.z * scale2); f[3] = f2bf(xv.w * scale2);
      f[4] = f2bf(yv.x * scale2); f[5] = f2bf(yv.y * scale2);
      f[6] = f2bf(yv.z * scale2); f[7] = f2bf(yv.w * scale2);
      qf[qt][ks] = __builtin_bit_cast(bf16x8, f);
    }
  }
  int kgo[4], vgo[2][2];
#pragma unroll
  for (int ks = 0; ks < 4; ++ks)
    kgo[ks] = ((wv * 16 + c) * 16 + ((qd + 4 * ks) ^ s3)) * 16;
#pragma unroll
  for (int dt = 0; dt < 2; ++dt)
#pragma unroll
    for (int kvs = 0; kvs < 2; ++kvs)
      vgo[dt][kvs] = ((wv * 32 + dt * 16 + c) * 8 + ((qd + 4 * kvs) ^ s3)) * 16;

  const char* kbase = ws + (size_t)(b * NT) * TILE_B;
  const char* vbase = ws + VWS_OFF + (size_t)(b * NT) * TILE_B;

  f32x4 oacc[2][4];
#pragma unroll
  for (int dt = 0; dt < 2; ++dt)
#pragma unroll
    for (int qt = 0; qt < 4; ++qt) oacc[dt][qt] = f32x4{0.f, 0.f, 0.f, 0.f};
  float l4[4] = {0.f, 0.f, 0.f, 0.f};
  f32x4 st[4];

  auto loadK = [&](bf16x8 (&dst)[4], int kt_) {
    const char* kb_ = kbase + (size_t)kt_ * TILE_B;
#pragma unroll
    for (int ks = 0; ks < 4; ++ks) dst[ks] = gload8v(kb_ + kgo[ks]);
  };
  auto loadV = [&](bf16x8 (&dst)[2][2], int kt_) {
    const char* vb_ = vbase + (size_t)kt_ * TILE_B;
#pragma unroll
    for (int dt = 0; dt < 2; ++dt)
#pragma unroll
      for (int kvs = 0; kvs < 2; ++kvs) dst[dt][kvs] = gload8v(vb_ + vgo[dt][kvs]);
  };
  auto qk = [&](bf16x8 (&kfr)[4]) {
    __builtin_amdgcn_s_setprio(1);
#pragma unroll
    for (int qt = 0; qt < 4; ++qt) {
      f32x4 acc = f32x4{0.f, 0.f, 0.f, 0.f};
#pragma unroll
      for (int ks = 0; ks < 4; ++ks)
        acc = __builtin_amdgcn_mfma_f32_16x16x32_bf16(kfr[ks], qf[qt][ks], acc, 0, 0, 0);
      st[qt] = acc;
    }
    __builtin_amdgcn_s_setprio(0);
  };
  auto smax = [&](short* pbuf, bool mask) {
    if (mask) {
#pragma unroll
      for (int qt = 0; qt < 4; ++qt)
#pragma unroll
        for (int r = 0; r < 4; ++r)
          if (wv * 16 + qd * 4 + r > qt * 16 + c) st[qt][r] = -1e30f;
    }
#pragma unroll
    for (int qt = 0; qt < 4; ++qt) {
      float p0 = __builtin_amdgcn_exp2f(st[qt][0] - 16.0f);
      float p1 = __builtin_amdgcn_exp2f(st[qt][1] - 16.0f);
      float p2 = __builtin_amdgcn_exp2f(st[qt][2] - 16.0f);
      float p3 = __builtin_amdgcn_exp2f(st[qt][3] - 16.0f);
      l4[qt] += (p0 + p1) + (p2 + p3);
      uint2 w; w.x = cvtpk(p0, p1); w.y = cvtpk(p2, p3);
      *(uint2*)&pbuf[(qt * 16 + c) * LDP + wv * 16 + qd * 4] = w;
    }
  };
  auto pv = [&](bf16x8 (&vfr)[2][2], const short* pbuf) {
#pragma unroll
    for (int kvs = 0; kvs < 2; ++kvs) {
      bf16x8 pf[4];
#pragma unroll
      for (int qt = 0; qt < 4; ++qt)
        pf[qt] = lds8(&pbuf[(qt * 16 + c) * LDP + kvs * 32 + qd * 8]);
      __builtin_amdgcn_s_setprio(1);
#pragma unroll
      for (int dt = 0; dt < 2; ++dt)
#pragma unroll
        for (int qt = 0; qt < 4; ++qt)
          oacc[dt][qt] = __builtin_amdgcn_mfma_f32_16x16x32_bf16(
              vfr[dt][kvs], pf[qt], oacc[dt][qt], 0, 0, 0);
      __builtin_amdgcn_s_setprio(0);
    }
  };
  auto bar = [&]() {
    asm volatile("s_waitcnt lgkmcnt(0)" ::: "memory");
    __builtin_amdgcn_s_barrier();
    asm volatile("" ::: "memory");
  };

  bf16x8 kf0[4], kf1[4], vf0[2][2], vf1[2][2];
  loadK(kf0, 0); loadV(vf0, 0);
  if (t >= 1) { loadK(kf1, 1); loadV(vf1, 1); }
  qk(kf0);
  smax(lds_p0, t == 0);
  bar();
  int kt = 0;
  while (kt + 1 <= t) {
    qk(kf1);
    if (kt + 2 <= t) loadK(kf0, kt + 2);
    pv(vf0, lds_p0);
    if (kt + 2 <= t) loadV(vf0, kt + 2);
    smax(lds_p1, kt + 1 == t);
    bar();
    ++kt;
    if (kt + 1 > t) break;
    qk(kf0);
    if (kt + 2 <= t) loadK(kf1, kt + 2);
    pv(vf1, lds_p1);
    if (kt + 2 <= t) loadV(vf1, kt + 2);
    smax(lds_p0, kt + 1 == t);
    bar();
    ++kt;
  }
  if (t & 1) pv(vf1, lds_p1);
  else       pv(vf0, lds_p0);

#pragma unroll
  for (int qt = 0; qt < 4; ++qt) {
    l4[qt] += __shfl_xor(l4[qt], 16);
    l4[qt] += __shfl_xor(l4[qt], 32);
  }
  if (qd == 0) {
#pragma unroll
    for (int qt = 0; qt < 4; ++qt) lds_l[wv][qt * 16 + c] = l4[qt];
  }
  __syncthreads();
  float lt[4];
#pragma unroll
  for (int qt = 0; qt < 4; ++qt)
    lt[qt] = lds_l[0][qt * 16 + c] + lds_l[1][qt * 16 + c] +
             lds_l[2][qt * 16 + c] + lds_l[3][qt * 16 + c];
#pragma unroll
  for (int qt = 0; qt < 4; ++qt) {
    float inv = 1.0f / lt[qt];
    float* ob = Out + (size_t)(b * S_LEN + q0 + qt * 16 + c) * DV + wv * 32;
#pragma unroll
    for (int dt = 0; dt < 2; ++dt) {
      f32x4 v = oacc[dt][qt] * inv;
      *(f32x4*)(ob + dt * 16 + qd * 4) = v;
    }
  }
}

// ---------------------------------------------------------------------------
// Fallback (ws too small): verified single-pass kernel, in-kernel convert.
// ---------------------------------------------------------------------------
__global__ __launch_bounds__(256)
void fa_fallback(const float* __restrict__ Q, const float* __restrict__ K,
                 const float* __restrict__ V, float* __restrict__ Out) {
  __shared__ __align__(16) short lds_k[BN * 136];
  __shared__ __align__(16) short lds_vt[DV * 72];
  __shared__ __align__(16) short lds_p[4 * 16 * LDP];

  const int bid = blockIdx.x;
  const int b = bid >> 5, t = bid & 31;
  const int q0 = t * BM;
  const int tid = threadIdx.x;
  const int wv = tid >> 6, ln = tid & 63;
  const int c = ln & 15, qd = ln >> 4;
  const float scale2 = 0.12751741f;
  const int qg = q0 + wv * 16 + c;

  bf16x8 qf[4];
  {
    const float* qrow = Q + (size_t)(b * S_LEN + qg) * DK + qd * 8;
#pragma unroll
    for (int t4 = 0; t4 < 4; ++t4) {
      float4 x = *(const float4*)(qrow + t4 * 32);
      float4 y = *(const float4*)(qrow + t4 * 32 + 4);
      s16x8 f;
      f[0] = f2bf(x.x * scale2); f[1] = f2bf(x.y * scale2);
      f[2] = f2bf(x.z * scale2); f[3] = f2bf(x.w * scale2);
      f[4] = f2bf(y.x * scale2); f[5] = f2bf(y.y * scale2);
      f[6] = f2bf(y.z * scale2); f[7] = f2bf(y.w * scale2);
      qf[t4] = __builtin_bit_cast(bf16x8, f);
    }
  }
  f32x4 oacc[8];
#pragma unroll
  for (int i = 0; i < 8; ++i) oacc[i] = f32x4{0.f, 0.f, 0.f, 0.f};
  float m_i = -1e30f, l_i = 0.f;
  const float* kbb = K + (size_t)b * S_LEN * DK;
  const float* vbb = V + (size_t)b * S_LEN * DV;
  short* pb = &lds_p[wv * 16 * LDP];

  for (int kt = 0; kt <= t; ++kt) {
    const int kv0 = kt * BN;
    __syncthreads();
    {
      const float* kb = kbb + (size_t)kv0 * DK;
#pragma unroll
      for (int it = 0; it < 8; ++it) {
        int flat = it * 256 + tid;
        int r = flat >> 5, d4 = flat & 31;
        float4 x = *(const float4*)(kb + r * DK + d4 * 4);
        s16x4 s;
        s[0] = f2bf(x.x); s[1] = f2bf(x.y); s[2] = f2bf(x.z); s[3] = f2bf(x.w);
        *(s16x4*)&lds_k[r * 136 + d4 * 4] = s;
      }
      const float* vb = vbb + (size_t)kv0 * DV;
#pragma unroll
      for (int it = 0; it < 8; ++it) {
        int flat = it * 256 + tid;
        int d = flat & 127, r0 = (flat >> 7) << 2;
        s16x4 s;
        s[0] = f2bf(vb[(r0 + 0) * DV + d]);
        s[1] = f2bf(vb[(r0 + 1) * DV + d]);
        s[2] = f2bf(vb[(r0 + 2) * DV + d]);
        s[3] = f2bf(vb[(r0 + 3) * DV + d]);
        *(s16x4*)&lds_vt[d * 72 + r0] = s;
      }
    }
    __syncthreads();
    f32x4 st[4];
#pragma unroll
    for (int cb = 0; cb < 4; ++cb) {
      f32x4 acc = f32x4{0.f, 0.f, 0.f, 0.f};
      const short* kr = &lds_k[(cb * 16 + c) * 136 + qd * 8];
#pragma unroll
      for (int t4 = 0; t4 < 4; ++t4)
        acc = __builtin_amdgcn_mfma_f32_16x16x32_bf16(lds8(kr + t4 * 32), qf[t4], acc, 0, 0, 0);
      st[cb] = acc;
    }
    if (kt == t) {
#pragma unroll
      for (int cb = 0; cb < 4; ++cb)
#pragma unroll
        for (int r = 0; r < 4; ++r)
          if (cb * 16 + qd * 4 + r > wv * 16 + c) st[cb][r] = -1e30f;
    }
    float tmax = -1e30f;
#pragma unroll
    for (int cb = 0; cb < 4; ++cb)
#pragma unroll
      for (int r = 0; r < 4; ++r) tmax = fmaxf(tmax, st[cb][r]);
    tmax = fmaxf(tmax, __shfl_xor(tmax, 16));
    tmax = fmaxf(tmax, __shfl_xor(tmax, 32));
    float mn = fmaxf(m_i, tmax);
    float al = __builtin_amdgcn_exp2f(m_i - mn);
    m_i = mn;
    float tsum = 0.f;
#pragma unroll
    for (int cb = 0; cb < 4; ++cb) {
      s16x4 pk;
#pragma unroll
      for (int r = 0; r < 4; ++r) {
        float p = __builtin_amdgcn_exp2f(st[cb][r] - m_i);
        tsum += p;
        pk[r] = f2bf(p);
      }
      *(s16x4*)&pb[c * LDP + cb * 16 + qd * 4] = pk;
    }
    tsum += __shfl_xor(tsum, 16);
    tsum += __shfl_xor(tsum, 32);
    l_i = l_i * al + tsum;
#pragma unroll
    for (int i = 0; i < 8; ++i)
#pragma unroll
      for (int r = 0; r < 4; ++r) oacc[i][r] *= al;
#pragma unroll
    for (int t2 = 0; t2 < 2; ++t2) {
      bf16x8 pf = lds8(&pb[c * LDP + t2 * 32 + qd * 8]);
#pragma unroll
      for (int cb2 = 0; cb2 < 8; ++cb2) {
        bf16x8 vf = lds8(&lds_vt[(cb2 * 16 + c) * 72 + t2 * 32 + qd * 8]);
        oacc[cb2] = __builtin_amdgcn_mfma_f32_16x16x32_bf16(vf, pf, oacc[cb2], 0, 0, 0);
      }
    }
  }
  float inv = 1.0f / l_i;
  float* ob = Out + (size_t)(b * S_LEN + qg) * DV;
#pragma unroll
  for (int cb2 = 0; cb2 < 8; ++cb2) {
    f32x4 v = oacc[cb2] * inv;
    *(f32x4*)(ob + cb2 * 16 + qd * 4) = v;
  }
}

extern "C" void kernel_launch(void* const* d_in, const int* in_sizes, int n_in,
                              void* d_out, int out_size, void* d_ws, size_t ws_size,
                              hipStream_t stream) {
  (void)in_sizes; (void)n_in; (void)out_size;
  const float* Q = (const float*)d_in[0];
  const float* K = (const float*)d_in[1];
  const float* V = (const float*)d_in[2];
  float* O = (float*)d_out;
  if (ws_size >= WS_NEED_SPLIT) {
    fa_convert<<<dim3(1024), dim3(256), 0, stream>>>(K, V, (char*)d_ws);
    fa_main_split<<<dim3(1024), dim3(256), 0, stream>>>(Q, (char*)d_ws, O);
    fa_combine<<<dim3(2048), dim3(256), 0, stream>>>(O, (const char*)d_ws);
  } else if (ws_size >= WS_NEED) {
    fa_convert<<<dim3(1024), dim3(256), 0, stream>>>(K, V, (char*)d_ws);
    fa_main_pair<<<dim3(512), dim3(256), 0, stream>>>(Q, (const char*)d_ws, O);
  } else {
    fa_fallback<<<dim3(512), dim3(256), 0, stream>>>(Q, K, V, O);
  }
}

// Round 5
// 139.077 us; speedup vs baseline: 2.5460x; 2.5460x over previous
//
#include <hip/hip_runtime.h>
#include <hip/hip_bf16.h>

#define S_LEN 2048
#define DK 128
#define DV 128
#define BM 64     // Q rows per block (4 waves, kv/d split across waves)
#define BN 64     // KV rows per tile
#define NT 32     // KV tiles per batch
#define LDP 72    // LDS P row stride (bf16)
#define TILE_B 16384                        // bytes per staged tile (64x128 bf16)
#define VWS_OFF ((size_t)16 * NT * TILE_B)  // 8.39 MB
#define WS_NEED ((size_t)2 * 16 * NT * TILE_B)
// split-KV partial buffers
#define PART_OFF WS_NEED                              // h=1 acc partial, 16.78 MB
#define PART_B   ((size_t)16 * S_LEN * DV * 4)
#define L0_OFF   (PART_OFF + PART_B)                  // l partials, 128 KB each
#define L1_OFF   (L0_OFF + (size_t)16 * S_LEN * 4)
#define WS_NEED_SPLIT (L1_OFF + (size_t)16 * S_LEN * 4)

typedef __attribute__((ext_vector_type(8))) short s16x8;
typedef __attribute__((ext_vector_type(4))) short s16x4;
typedef __attribute__((ext_vector_type(8))) __bf16 bf16x8;
typedef __attribute__((ext_vector_type(4))) float f32x4;

__device__ __forceinline__ short f2bf(float f) {
  unsigned u = __builtin_bit_cast(unsigned, f);
  u += 0x7FFFu + ((u >> 16) & 1u);
  return (short)(u >> 16);
}
__device__ __forceinline__ bf16x8 lds8(const short* p) {
  return __builtin_bit_cast(bf16x8, *(const s16x8*)p);
}
__device__ __forceinline__ bf16x8 gload8v(const char* p) {
  return __builtin_bit_cast(bf16x8, *(const s16x8*)p);
}
// packed f32x2 -> bf16x2 (RNE): low = a, high = b
__device__ __forceinline__ unsigned cvtpk(float a, float b) {
  unsigned r;
  asm("v_cvt_pk_bf16_f32 %0, %1, %2" : "=v"(r) : "v"(a), "v"(b));
  return r;
}

// ---------------------------------------------------------------------------
// Pass 1: convert K -> bf16 and V -> bf16-transposed, tile-major, chunks
// pre-permuted in the XOR-swizzled order (addresses fold the same XOR).
//   K tile:  chunk(r,cix) at position r*16 + (cix ^ (r&7))
//   Vt tile: chunk(d,cix) at position d*8 + (cix ^ (d&7))
// ---------------------------------------------------------------------------
__global__ __launch_bounds__(256)
void fa_convert(const float* __restrict__ K, const float* __restrict__ V,
                char* __restrict__ ws) {
  __shared__ short tlds[BN * 130];  // 16640 B, V path only
  const int bid = blockIdx.x;
  const int tid = threadIdx.x;
  if (bid < 512) {  // K: bid = b*32 + kt
    const int b = bid >> 5, kt = bid & 31;
    const float* kb = K + (size_t)(b * S_LEN + kt * BN) * DK;
    short* out = (short*)(ws + (size_t)bid * TILE_B);
#pragma unroll
    for (int it = 0; it < 4; ++it) {
      int o = it * 256 + tid;
      int r = o >> 4, cix = o & 15;
      const float* src = kb + r * DK + cix * 8;
      float4 x = *(const float4*)src;
      float4 y = *(const float4*)(src + 4);
      s16x8 f;
      f[0] = f2bf(x.x); f[1] = f2bf(x.y); f[2] = f2bf(x.z); f[3] = f2bf(x.w);
      f[4] = f2bf(y.x); f[5] = f2bf(y.y); f[6] = f2bf(y.z); f[7] = f2bf(y.w);
      int pos = r * 16 + (cix ^ (r & 7));
      *(s16x8*)(out + pos * 8) = f;
    }
  } else {  // V transpose via LDS: vb = b*32 + kt
    const int vb = bid - 512;
    const float* vbase = V + (size_t)((vb >> 5) * S_LEN + (vb & 31) * BN) * DV;
    short* out = (short*)(ws + VWS_OFF + (size_t)vb * TILE_B);
#pragma unroll
    for (int i = 0; i < 8; ++i) {
      int idx = i * 256 + tid;        // float4 index, 2048 total
      int r = idx >> 5, c4 = idx & 31;
      float4 x = *(const float4*)(vbase + r * DV + c4 * 4);
      unsigned lo = ((unsigned)(unsigned short)f2bf(x.y) << 16) |
                    (unsigned short)f2bf(x.x);
      unsigned hi = ((unsigned)(unsigned short)f2bf(x.w) << 16) |
                    (unsigned short)f2bf(x.z);
      *(unsigned*)&tlds[r * 130 + c4 * 4] = lo;
      *(unsigned*)&tlds[r * 130 + c4 * 4 + 2] = hi;
    }
    __syncthreads();
#pragma unroll
    for (int i = 0; i < 2; ++i) {
      int idx = i * 256 + tid;        // pair index, 512 total
      int dp = idx >> 3, cix = idx & 7;
      int d = dp * 2;
      s16x8 f0, f1;
#pragma unroll
      for (int j = 0; j < 8; ++j) {
        int r = cix * 8 + j;
        unsigned two = *(const unsigned*)&tlds[r * 130 + d];
        f0[j] = (short)(two & 0xFFFFu);
        f1[j] = (short)(two >> 16);
      }
      int p0 = d * 8 + (cix ^ (d & 7));
      int p1 = (d + 1) * 8 + (cix ^ ((d + 1) & 7));
      *(s16x8*)(out + p0 * 8) = f0;
      *(s16x8*)(out + p1 * 8) = f1;
    }
  }
}

// ---------------------------------------------------------------------------
// Pass 2 (split-KV): 1024 blocks, block = (batch, q-tile t, half h).
// h=0 covers kv tiles [0,(t+2)/2), h=1 covers [(t+2)/2, t+1) -> max 16
// steps/block (was 32). Fixed-m softmax (m=16) makes partials combine by
// PLAIN ADDITION: h=0 writes unnormalized acc to Out, h=1 to ws; fa_combine
// adds and normalizes. Deterministic, no atomics.
// __launch_bounds__(256,2): R4's (256,4) forced VGPR 180->64 and spilled
// ~1 GB scratch/dispatch (FETCH 490 MB). At (256,2) this kernel compiles
// to 128 VGPR (R3-verified) which ALREADY permits 4 waves/SIMD -> the
// 1024-block grid gives 4 blocks/CU co-resident without any spill.
// Ping-pong barrier schedule + direct-L2 frag reads as in R3.
// XCD remap: 2 batches per XCD; heaviest (t=31) blocks dispatch first.
// ---------------------------------------------------------------------------
__global__ __launch_bounds__(256, 2)
void fa_main_split(const float* __restrict__ Q, char* __restrict__ ws,
                   float* __restrict__ Out) {
  __shared__ __align__(16) short lds_p0[64 * LDP];
  __shared__ __align__(16) short lds_p1[64 * LDP];
  __shared__ float lds_l[4][64];

  const int bid = blockIdx.x;           // [0,1024)
  const int x = bid & 7, j = bid >> 3;  // j in [0,128)
  const int u = j >> 1;                 // [0,64): (t,h), heavy-first
  const int b = x + 8 * (j & 1);
  const int t = 31 - (u >> 1);
  const int h = u & 1;
  const int lo = h ? ((t + 2) >> 1) : 0;
  const int hi = h ? (t + 1) : ((t + 2) >> 1);
  const int n  = hi - lo;

  const int q0  = t * BM;
  const int tid = threadIdx.x;
  const int wv  = tid >> 6, ln = tid & 63;
  const int c   = ln & 15, qd = ln >> 4;
  const int s3  = c & 7;
  const float scale2 = 0.12751741f;      // log2(e)/sqrt(128), folded into Q

  // Q frags for ALL 64 q rows: qf[qt][ks] = Q[q0+qt*16+c][ks*32+qd*8 ..+8]*scale2
  bf16x8 qf[4][4];
#pragma unroll
  for (int qt = 0; qt < 4; ++qt) {
    const float* qrow = Q + (size_t)(b * S_LEN + q0 + qt * 16 + c) * DK + qd * 8;
#pragma unroll
    for (int ks = 0; ks < 4; ++ks) {
      float4 xv = *(const float4*)(qrow + ks * 32);
      float4 yv = *(const float4*)(qrow + ks * 32 + 4);
      s16x8 f;
      f[0] = f2bf(xv.x * scale2); f[1] = f2bf(xv.y * scale2);
      f[2] = f2bf(xv.z * scale2); f[3] = f2bf(xv.w * scale2);
      f[4] = f2bf(yv.x * scale2); f[5] = f2bf(yv.y * scale2);
      f[6] = f2bf(yv.z * scale2); f[7] = f2bf(yv.w * scale2);
      qf[qt][ks] = __builtin_bit_cast(bf16x8, f);
    }
  }

  // step-invariant global frag byte offsets within a tile
  int kgo[4], vgo[2][2];
#pragma unroll
  for (int ks = 0; ks < 4; ++ks)
    kgo[ks] = ((wv * 16 + c) * 16 + ((qd + 4 * ks) ^ s3)) * 16;
#pragma unroll
  for (int dt = 0; dt < 2; ++dt)
#pragma unroll
    for (int kvs = 0; kvs < 2; ++kvs)
      vgo[dt][kvs] = ((wv * 32 + dt * 16 + c) * 8 + ((qd + 4 * kvs) ^ s3)) * 16;

  const char* kbase = ws + (size_t)(b * NT) * TILE_B;
  const char* vbase = ws + VWS_OFF + (size_t)(b * NT) * TILE_B;

  f32x4 oacc[2][4];
#pragma unroll
  for (int dt = 0; dt < 2; ++dt)
#pragma unroll
    for (int qt = 0; qt < 4; ++qt) oacc[dt][qt] = f32x4{0.f, 0.f, 0.f, 0.f};
  float l4[4] = {0.f, 0.f, 0.f, 0.f};
  f32x4 st[4];

  auto loadK = [&](bf16x8 (&dst)[4], int kt_) {
    const char* kb_ = kbase + (size_t)kt_ * TILE_B;
#pragma unroll
    for (int ks = 0; ks < 4; ++ks) dst[ks] = gload8v(kb_ + kgo[ks]);
  };
  auto loadV = [&](bf16x8 (&dst)[2][2], int kt_) {
    const char* vb_ = vbase + (size_t)kt_ * TILE_B;
#pragma unroll
    for (int dt = 0; dt < 2; ++dt)
#pragma unroll
      for (int kvs = 0; kvs < 2; ++kvs) dst[dt][kvs] = gload8v(vb_ + vgo[dt][kvs]);
  };
  auto qk = [&](bf16x8 (&kfr)[4]) {
    __builtin_amdgcn_s_setprio(1);
#pragma unroll
    for (int qt = 0; qt < 4; ++qt) {
      f32x4 acc = f32x4{0.f, 0.f, 0.f, 0.f};
#pragma unroll
      for (int ks = 0; ks < 4; ++ks)
        acc = __builtin_amdgcn_mfma_f32_16x16x32_bf16(kfr[ks], qf[qt][ks], acc, 0, 0, 0);
      st[qt] = acc;
    }
    __builtin_amdgcn_s_setprio(0);
  };
  auto smax = [&](short* pbuf, bool mask) {
    if (mask) {
#pragma unroll
      for (int qt = 0; qt < 4; ++qt)
#pragma unroll
        for (int r = 0; r < 4; ++r)
          if (wv * 16 + qd * 4 + r > qt * 16 + c) st[qt][r] = -1e30f;
    }
#pragma unroll
    for (int qt = 0; qt < 4; ++qt) {
      float p0 = __builtin_amdgcn_exp2f(st[qt][0] - 16.0f);
      float p1 = __builtin_amdgcn_exp2f(st[qt][1] - 16.0f);
      float p2 = __builtin_amdgcn_exp2f(st[qt][2] - 16.0f);
      float p3 = __builtin_amdgcn_exp2f(st[qt][3] - 16.0f);
      l4[qt] += (p0 + p1) + (p2 + p3);
      uint2 w; w.x = cvtpk(p0, p1); w.y = cvtpk(p2, p3);
      *(uint2*)&pbuf[(qt * 16 + c) * LDP + wv * 16 + qd * 4] = w;
    }
  };
  auto pv = [&](bf16x8 (&vfr)[2][2], const short* pbuf) {
#pragma unroll
    for (int kvs = 0; kvs < 2; ++kvs) {
      bf16x8 pf[4];
#pragma unroll
      for (int qt = 0; qt < 4; ++qt)
        pf[qt] = lds8(&pbuf[(qt * 16 + c) * LDP + kvs * 32 + qd * 8]);
      __builtin_amdgcn_s_setprio(1);
#pragma unroll
      for (int dt = 0; dt < 2; ++dt)
#pragma unroll
        for (int qt = 0; qt < 4; ++qt)
          oacc[dt][qt] = __builtin_amdgcn_mfma_f32_16x16x32_bf16(
              vfr[dt][kvs], pf[qt], oacc[dt][qt], 0, 0, 0);
      __builtin_amdgcn_s_setprio(0);
    }
  };
  auto bar = [&]() {
    asm volatile("s_waitcnt lgkmcnt(0)" ::: "memory");
    __builtin_amdgcn_s_barrier();
    asm volatile("" ::: "memory");
  };

  // named double buffers (no runtime indexing -> stays in registers)
  bf16x8 kf0[4], kf1[4], vf0[2][2], vf1[2][2];

  if (n > 0) {
    loadK(kf0, lo); loadV(vf0, lo);
    if (n >= 2) { loadK(kf1, lo + 1); loadV(vf1, lo + 1); }
    qk(kf0);
    smax(lds_p0, lo == t);
    bar();
    // invariant at loop top (i even): P(lo+i) in pb0, kf1/vf1 hold tile lo+i+1
    int i = 0;
    while (i + 1 < n) {
      qk(kf1);
      if (i + 2 < n) loadK(kf0, lo + i + 2);
      pv(vf0, lds_p0);
      if (i + 2 < n) loadV(vf0, lo + i + 2);
      smax(lds_p1, lo + i + 1 == t);
      bar();
      ++i;
      if (i + 1 >= n) break;
      qk(kf0);
      if (i + 2 < n) loadK(kf1, lo + i + 2);
      pv(vf1, lds_p1);
      if (i + 2 < n) loadV(vf1, lo + i + 2);
      smax(lds_p0, lo + i + 1 == t);
      bar();
      ++i;
    }
    if (i & 1) pv(vf1, lds_p1);
    else       pv(vf0, lds_p0);
  }

  // l reduction: over qd lanes (shfl) then over waves (LDS)
#pragma unroll
  for (int qt = 0; qt < 4; ++qt) {
    l4[qt] += __shfl_xor(l4[qt], 16);
    l4[qt] += __shfl_xor(l4[qt], 32);
  }
  if (qd == 0) {
#pragma unroll
    for (int qt = 0; qt < 4; ++qt) lds_l[wv][qt * 16 + c] = l4[qt];
  }
  __syncthreads();
  float lt[4];
#pragma unroll
  for (int qt = 0; qt < 4; ++qt)
    lt[qt] = lds_l[0][qt * 16 + c] + lds_l[1][qt * 16 + c] +
             lds_l[2][qt * 16 + c] + lds_l[3][qt * 16 + c];

  // epilogue: store UNNORMALIZED partial acc + l; combine kernel finishes
  float* obase = h ? (float*)(ws + PART_OFF) : Out;
  float* lbase = (float*)(ws + (h ? L1_OFF : L0_OFF)) + (size_t)b * S_LEN;
  if (wv == 0 && qd == 0) {
#pragma unroll
    for (int qt = 0; qt < 4; ++qt) lbase[q0 + qt * 16 + c] = lt[qt];
  }
#pragma unroll
  for (int qt = 0; qt < 4; ++qt) {
    float* ob = obase + (size_t)(b * S_LEN + q0 + qt * 16 + c) * DV + wv * 32;
#pragma unroll
    for (int dt = 0; dt < 2; ++dt)
      *(f32x4*)(ob + dt * 16 + qd * 4) = oacc[dt][qt];
  }
}

// Combine: Out = (Out + P1) / (l0 + l1). 2048 blocks x 256 threads x 8 floats.
__global__ __launch_bounds__(256)
void fa_combine(float* __restrict__ Out, const char* __restrict__ ws) {
  const float* P1 = (const float*)(ws + PART_OFF);
  const float* L0 = (const float*)(ws + L0_OFF);
  const float* L1 = (const float*)(ws + L1_OFF);
  const int base = (blockIdx.x * 256 + threadIdx.x) * 8;
  const int q = base >> 7;  // global row in [0, 16*2048)
  float inv = 1.0f / (L0[q] + L1[q]);
  f32x4 a0 = *(const f32x4*)(Out + base);
  f32x4 a1 = *(const f32x4*)(P1 + base);
  f32x4 b0 = *(const f32x4*)(Out + base + 4);
  f32x4 b1 = *(const f32x4*)(P1 + base + 4);
  *(f32x4*)(Out + base)     = (a0 + a1) * inv;
  *(f32x4*)(Out + base + 4) = (b0 + b1) * inv;
}

// ---------------------------------------------------------------------------
// Mid-tier (ws fits KV only): R3's verified ping-pong kernel, 512 blocks.
// ---------------------------------------------------------------------------
__global__ __launch_bounds__(256, 2)
void fa_main_pair(const float* __restrict__ Q, const char* __restrict__ ws,
                  float* __restrict__ Out) {
  __shared__ __align__(16) short lds_p0[64 * LDP];
  __shared__ __align__(16) short lds_p1[64 * LDP];
  __shared__ float lds_l[4][64];

  const int bid = blockIdx.x;
  const int x = bid & 7, j = bid >> 3;
  int b, t;
  if (j < 32) { b = x + 8 * (j & 1); t = 16 + (j >> 1); }
  else        { int jj = j - 32; b = x + 8 * (jj & 1); t = 15 - (jj >> 1); }
  const int q0  = t * BM;
  const int tid = threadIdx.x;
  const int wv  = tid >> 6, ln = tid & 63;
  const int c   = ln & 15, qd = ln >> 4;
  const int s3  = c & 7;
  const float scale2 = 0.12751741f;

  bf16x8 qf[4][4];
#pragma unroll
  for (int qt = 0; qt < 4; ++qt) {
    const float* qrow = Q + (size_t)(b * S_LEN + q0 + qt * 16 + c) * DK + qd * 8;
#pragma unroll
    for (int ks = 0; ks < 4; ++ks) {
      float4 xv = *(const float4*)(qrow + ks * 32);
      float4 yv = *(const float4*)(qrow + ks * 32 + 4);
      s16x8 f;
      f[0] = f2bf(xv.x * scale2); f[1] = f2bf(xv.y * scale2);
      f[2] = f2bf(xv.z * scale2); f[3] = f2bf(xv.w * scale2);
      f[4] = f2bf(yv.x * scale2); f[5] = f2bf(yv.y * scale2);
      f[6] = f2bf(yv.z * scale2); f[7] = f2bf(yv.w * scale2);
      qf[qt][ks] = __builtin_bit_cast(bf16x8, f);
    }
  }
  int kgo[4], vgo[2][2];
#pragma unroll
  for (int ks = 0; ks < 4; ++ks)
    kgo[ks] = ((wv * 16 + c) * 16 + ((qd + 4 * ks) ^ s3)) * 16;
#pragma unroll
  for (int dt = 0; dt < 2; ++dt)
#pragma unroll
    for (int kvs = 0; kvs < 2; ++kvs)
      vgo[dt][kvs] = ((wv * 32 + dt * 16 + c) * 8 + ((qd + 4 * kvs) ^ s3)) * 16;

  const char* kbase = ws + (size_t)(b * NT) * TILE_B;
  const char* vbase = ws + VWS_OFF + (size_t)(b * NT) * TILE_B;

  f32x4 oacc[2][4];
#pragma unroll
  for (int dt = 0; dt < 2; ++dt)
#pragma unroll
    for (int qt = 0; qt < 4; ++qt) oacc[dt][qt] = f32x4{0.f, 0.f, 0.f, 0.f};
  float l4[4] = {0.f, 0.f, 0.f, 0.f};
  f32x4 st[4];

  auto loadK = [&](bf16x8 (&dst)[4], int kt_) {
    const char* kb_ = kbase + (size_t)kt_ * TILE_B;
#pragma unroll
    for (int ks = 0; ks < 4; ++ks) dst[ks] = gload8v(kb_ + kgo[ks]);
  };
  auto loadV = [&](bf16x8 (&dst)[2][2], int kt_) {
    const char* vb_ = vbase + (size_t)kt_ * TILE_B;
#pragma unroll
    for (int dt = 0; dt < 2; ++dt)
#pragma unroll
      for (int kvs = 0; kvs < 2; ++kvs) dst[dt][kvs] = gload8v(vb_ + vgo[dt][kvs]);
  };
  auto qk = [&](bf16x8 (&kfr)[4]) {
    __builtin_amdgcn_s_setprio(1);
#pragma unroll
    for (int qt = 0; qt < 4; ++qt) {
      f32x4 acc = f32x4{0.f, 0.f, 0.f, 0.f};
#pragma unroll
      for (int ks = 0; ks < 4; ++ks)
        acc = __builtin_amdgcn_mfma_f32_16x16x32_bf16(kfr[ks], qf[qt][ks], acc, 0, 0, 0);
      st[qt] = acc;
    }
    __builtin_amdgcn_s_setprio(0);
  };
  auto smax = [&](short* pbuf, bool mask) {
    if (mask) {
#pragma unroll
      for (int qt = 0; qt < 4; ++qt)
#pragma unroll
        for (int r = 0; r < 4; ++r)
          if (wv * 16 + qd * 4 + r > qt * 16 + c) st[qt][r] = -1e30f;
    }
#pragma unroll
    for (int qt = 0; qt < 4; ++qt) {
      float p0 = __builtin_amdgcn_exp2f(st[qt][0] - 16.0f);
      float p1 = __builtin_amdgcn_exp2f(st[qt][1] - 16.0f);
      float p2 = __builtin_amdgcn_exp2f(st[qt][2] - 16.0f);
      float p3 = __builtin_amdgcn_exp2f(st[qt][3] - 16.0f);
      l4[qt] += (p0 + p1) + (p2 + p3);
      uint2 w; w.x = cvtpk(p0, p1); w.y = cvtpk(p2, p3);
      *(uint2*)&pbuf[(qt * 16 + c) * LDP + wv * 16 + qd * 4] = w;
    }
  };
  auto pv = [&](bf16x8 (&vfr)[2][2], const short* pbuf) {
#pragma unroll
    for (int kvs = 0; kvs < 2; ++kvs) {
      bf16x8 pf[4];
#pragma unroll
      for (int qt = 0; qt < 4; ++qt)
        pf[qt] = lds8(&pbuf[(qt * 16 + c) * LDP + kvs * 32 + qd * 8]);
      __builtin_amdgcn_s_setprio(1);
#pragma unroll
      for (int dt = 0; dt < 2; ++dt)
#pragma unroll
        for (int qt = 0; qt < 4; ++qt)
          oacc[dt][qt] = __builtin_amdgcn_mfma_f32_16x16x32_bf16(
              vfr[dt][kvs], pf[qt], oacc[dt][qt], 0, 0, 0);
      __builtin_amdgcn_s_setprio(0);
    }
  };
  auto bar = [&]() {
    asm volatile("s_waitcnt lgkmcnt(0)" ::: "memory");
    __builtin_amdgcn_s_barrier();
    asm volatile("" ::: "memory");
  };

  bf16x8 kf0[4], kf1[4], vf0[2][2], vf1[2][2];
  loadK(kf0, 0); loadV(vf0, 0);
  if (t >= 1) { loadK(kf1, 1); loadV(vf1, 1); }
  qk(kf0);
  smax(lds_p0, t == 0);
  bar();
  int kt = 0;
  while (kt + 1 <= t) {
    qk(kf1);
    if (kt + 2 <= t) loadK(kf0, kt + 2);
    pv(vf0, lds_p0);
    if (kt + 2 <= t) loadV(vf0, kt + 2);
    smax(lds_p1, kt + 1 == t);
    bar();
    ++kt;
    if (kt + 1 > t) break;
    qk(kf0);
    if (kt + 2 <= t) loadK(kf1, kt + 2);
    pv(vf1, lds_p1);
    if (kt + 2 <= t) loadV(vf1, kt + 2);
    smax(lds_p0, kt + 1 == t);
    bar();
    ++kt;
  }
  if (t & 1) pv(vf1, lds_p1);
  else       pv(vf0, lds_p0);

#pragma unroll
  for (int qt = 0; qt < 4; ++qt) {
    l4[qt] += __shfl_xor(l4[qt], 16);
    l4[qt] += __shfl_xor(l4[qt], 32);
  }
  if (qd == 0) {
#pragma unroll
    for (int qt = 0; qt < 4; ++qt) lds_l[wv][qt * 16 + c] = l4[qt];
  }
  __syncthreads();
  float lt[4];
#pragma unroll
  for (int qt = 0; qt < 4; ++qt)
    lt[qt] = lds_l[0][qt * 16 + c] + lds_l[1][qt * 16 + c] +
             lds_l[2][qt * 16 + c] + lds_l[3][qt * 16 + c];
#pragma unroll
  for (int qt = 0; qt < 4; ++qt) {
    float inv = 1.0f / lt[qt];
    float* ob = Out + (size_t)(b * S_LEN + q0 + qt * 16 + c) * DV + wv * 32;
#pragma unroll
    for (int dt = 0; dt < 2; ++dt) {
      f32x4 v = oacc[dt][qt] * inv;
      *(f32x4*)(ob + dt * 16 + qd * 4) = v;
    }
  }
}

// ---------------------------------------------------------------------------
// Fallback (ws too small): verified single-pass kernel, in-kernel convert.
// ---------------------------------------------------------------------------
__global__ __launch_bounds__(256)
void fa_fallback(const float* __restrict__ Q, const float* __restrict__ K,
                 const float* __restrict__ V, float* __restrict__ Out) {
  __shared__ __align__(16) short lds_k[BN * 136];
  __shared__ __align__(16) short lds_vt[DV * 72];
  __shared__ __align__(16) short lds_p[4 * 16 * LDP];

  const int bid = blockIdx.x;
  const int b = bid >> 5, t = bid & 31;
  const int q0 = t * BM;
  const int tid = threadIdx.x;
  const int wv = tid >> 6, ln = tid & 63;
  const int c = ln & 15, qd = ln >> 4;
  const float scale2 = 0.12751741f;
  const int qg = q0 + wv * 16 + c;

  bf16x8 qf[4];
  {
    const float* qrow = Q + (size_t)(b * S_LEN + qg) * DK + qd * 8;
#pragma unroll
    for (int t4 = 0; t4 < 4; ++t4) {
      float4 x = *(const float4*)(qrow + t4 * 32);
      float4 y = *(const float4*)(qrow + t4 * 32 + 4);
      s16x8 f;
      f[0] = f2bf(x.x * scale2); f[1] = f2bf(x.y * scale2);
      f[2] = f2bf(x.z * scale2); f[3] = f2bf(x.w * scale2);
      f[4] = f2bf(y.x * scale2); f[5] = f2bf(y.y * scale2);
      f[6] = f2bf(y.z * scale2); f[7] = f2bf(y.w * scale2);
      qf[t4] = __builtin_bit_cast(bf16x8, f);
    }
  }
  f32x4 oacc[8];
#pragma unroll
  for (int i = 0; i < 8; ++i) oacc[i] = f32x4{0.f, 0.f, 0.f, 0.f};
  float m_i = -1e30f, l_i = 0.f;
  const float* kbb = K + (size_t)b * S_LEN * DK;
  const float* vbb = V + (size_t)b * S_LEN * DV;
  short* pb = &lds_p[wv * 16 * LDP];

  for (int kt = 0; kt <= t; ++kt) {
    const int kv0 = kt * BN;
    __syncthreads();
    {
      const float* kb = kbb + (size_t)kv0 * DK;
#pragma unroll
      for (int it = 0; it < 8; ++it) {
        int flat = it * 256 + tid;
        int r = flat >> 5, d4 = flat & 31;
        float4 x = *(const float4*)(kb + r * DK + d4 * 4);
        s16x4 s;
        s[0] = f2bf(x.x); s[1] = f2bf(x.y); s[2] = f2bf(x.z); s[3] = f2bf(x.w);
        *(s16x4*)&lds_k[r * 136 + d4 * 4] = s;
      }
      const float* vb = vbb + (size_t)kv0 * DV;
#pragma unroll
      for (int it = 0; it < 8; ++it) {
        int flat = it * 256 + tid;
        int d = flat & 127, r0 = (flat >> 7) << 2;
        s16x4 s;
        s[0] = f2bf(vb[(r0 + 0) * DV + d]);
        s[1] = f2bf(vb[(r0 + 1) * DV + d]);
        s[2] = f2bf(vb[(r0 + 2) * DV + d]);
        s[3] = f2bf(vb[(r0 + 3) * DV + d]);
        *(s16x4*)&lds_vt[d * 72 + r0] = s;
      }
    }
    __syncthreads();
    f32x4 st[4];
#pragma unroll
    for (int cb = 0; cb < 4; ++cb) {
      f32x4 acc = f32x4{0.f, 0.f, 0.f, 0.f};
      const short* kr = &lds_k[(cb * 16 + c) * 136 + qd * 8];
#pragma unroll
      for (int t4 = 0; t4 < 4; ++t4)
        acc = __builtin_amdgcn_mfma_f32_16x16x32_bf16(lds8(kr + t4 * 32), qf[t4], acc, 0, 0, 0);
      st[cb] = acc;
    }
    if (kt == t) {
#pragma unroll
      for (int cb = 0; cb < 4; ++cb)
#pragma unroll
        for (int r = 0; r < 4; ++r)
          if (cb * 16 + qd * 4 + r > wv * 16 + c) st[cb][r] = -1e30f;
    }
    float tmax = -1e30f;
#pragma unroll
    for (int cb = 0; cb < 4; ++cb)
#pragma unroll
      for (int r = 0; r < 4; ++r) tmax = fmaxf(tmax, st[cb][r]);
    tmax = fmaxf(tmax, __shfl_xor(tmax, 16));
    tmax = fmaxf(tmax, __shfl_xor(tmax, 32));
    float mn = fmaxf(m_i, tmax);
    float al = __builtin_amdgcn_exp2f(m_i - mn);
    m_i = mn;
    float tsum = 0.f;
#pragma unroll
    for (int cb = 0; cb < 4; ++cb) {
      s16x4 pk;
#pragma unroll
      for (int r = 0; r < 4; ++r) {
        float p = __builtin_amdgcn_exp2f(st[cb][r] - m_i);
        tsum += p;
        pk[r] = f2bf(p);
      }
      *(s16x4*)&pb[c * LDP + cb * 16 + qd * 4] = pk;
    }
    tsum += __shfl_xor(tsum, 16);
    tsum += __shfl_xor(tsum, 32);
    l_i = l_i * al + tsum;
#pragma unroll
    for (int i = 0; i < 8; ++i)
#pragma unroll
      for (int r = 0; r < 4; ++r) oacc[i][r] *= al;
#pragma unroll
    for (int t2 = 0; t2 < 2; ++t2) {
      bf16x8 pf = lds8(&pb[c * LDP + t2 * 32 + qd * 8]);
#pragma unroll
      for (int cb2 = 0; cb2 < 8; ++cb2) {
        bf16x8 vf = lds8(&lds_vt[(cb2 * 16 + c) * 72 + t2 * 32 + qd * 8]);
        oacc[cb2] = __builtin_amdgcn_mfma_f32_16x16x32_bf16(vf, pf, oacc[cb2], 0, 0, 0);
      }
    }
  }
  float inv = 1.0f / l_i;
  float* ob = Out + (size_t)(b * S_LEN + qg) * DV;
#pragma unroll
  for (int cb2 = 0; cb2 < 8; ++cb2) {
    f32x4 v = oacc[cb2] * inv;
    *(f32x4*)(ob + cb2 * 16 + qd * 4) = v;
  }
}

extern "C" void kernel_launch(void* const* d_in, const int* in_sizes, int n_in,
                              void* d_out, int out_size, void* d_ws, size_t ws_size,
                              hipStream_t stream) {
  (void)in_sizes; (void)n_in; (void)out_size;
  const float* Q = (const float*)d_in[0];
  const float* K = (const float*)d_in[1];
  const float* V = (const float*)d_in[2];
  float* O = (float*)d_out;
  if (ws_size >= WS_NEED_SPLIT) {
    fa_convert<<<dim3(1024), dim3(256), 0, stream>>>(K, V, (char*)d_ws);
    fa_main_split<<<dim3(1024), dim3(256), 0, stream>>>(Q, (char*)d_ws, O);
    fa_combine<<<dim3(2048), dim3(256), 0, stream>>>(O, (const char*)d_ws);
  } else if (ws_size >= WS_NEED) {
    fa_convert<<<dim3(1024), dim3(256), 0, stream>>>(K, V, (char*)d_ws);
    fa_main_pair<<<dim3(512), dim3(256), 0, stream>>>(Q, (const char*)d_ws, O);
  } else {
    fa_fallback<<<dim3(512), dim3(256), 0, stream>>>(Q, K, V, O);
  }
}

// Round 6
// 134.266 us; speedup vs baseline: 2.6372x; 1.0358x over previous
//
#include <hip/hip_runtime.h>
#include <hip/hip_bf16.h>

#define S_LEN 2048
#define DK 128
#define DV 128
#define BM 64     // Q rows per block (pair kernel)
#define BN 64     // KV rows per ws tile
#define NT 32     // KV 64-tiles per batch
#define LDP 72    // LDS P row stride (pair kernel)
#define TILE_B 16384                        // bytes per staged 64x128 bf16 tile
#define VWS_OFF ((size_t)16 * NT * TILE_B)  // 8.39 MB
#define WS_NEED ((size_t)2 * 16 * NT * TILE_B)
// split-KV partial buffers
#define PART_OFF WS_NEED                              // h=1 acc partial, 16.78 MB
#define PART_B   ((size_t)16 * S_LEN * DV * 4)
#define L0_OFF   (PART_OFF + PART_B)                  // l partials, 128 KB each
#define L1_OFF   (L0_OFF + (size_t)16 * S_LEN * 4)
#define WS_NEED_SPLIT (L1_OFF + (size_t)16 * S_LEN * 4)

typedef __attribute__((ext_vector_type(8))) short s16x8;
typedef __attribute__((ext_vector_type(4))) short s16x4;
typedef __attribute__((ext_vector_type(8))) __bf16 bf16x8;
typedef __attribute__((ext_vector_type(4))) float f32x4;
typedef __attribute__((ext_vector_type(16))) float f32x16;
typedef __attribute__((ext_vector_type(4))) unsigned u32x4;

__device__ __forceinline__ short f2bf(float f) {
  unsigned u = __builtin_bit_cast(unsigned, f);
  u += 0x7FFFu + ((u >> 16) & 1u);
  return (short)(u >> 16);
}
__device__ __forceinline__ bf16x8 lds8(const short* p) {
  return __builtin_bit_cast(bf16x8, *(const s16x8*)p);
}
__device__ __forceinline__ bf16x8 gload8v(const char* p) {
  return __builtin_bit_cast(bf16x8, *(const s16x8*)p);
}
// packed f32x2 -> bf16x2 (RNE): low = a, high = b
__device__ __forceinline__ unsigned cvtpk(float a, float b) {
  unsigned r;
  asm("v_cvt_pk_bf16_f32 %0, %1, %2" : "=v"(r) : "v"(a), "v"(b));
  return r;
}
// v_permlane32_swap_b32: a'[l] = l<32 ? a[l] : b[l-32];
//                        b'[l] = l<32 ? a[l+32] : b[l]
__device__ __forceinline__ void plswap(unsigned& a, unsigned& b) {
  asm volatile("s_nop 1\n\tv_permlane32_swap_b32 %0, %1" : "+v"(a), "+v"(b));
}

// ---------------------------------------------------------------------------
// Pass 1: convert K -> bf16 and V -> bf16-transposed, tile-major, chunks
// pre-permuted in the XOR-swizzled order (addresses fold the same XOR).
//   K tile:  chunk(r,cix) at position r*16 + (cix ^ (r&7))
//   Vt tile: chunk(d,cix) at position d*8 + (cix ^ (d&7))
// ---------------------------------------------------------------------------
__global__ __launch_bounds__(256)
void fa_convert(const float* __restrict__ K, const float* __restrict__ V,
                char* __restrict__ ws) {
  __shared__ short tlds[BN * 130];  // 16640 B, V path only
  const int bid = blockIdx.x;
  const int tid = threadIdx.x;
  if (bid < 512) {  // K: bid = b*32 + kt
    const int b = bid >> 5, kt = bid & 31;
    const float* kb = K + (size_t)(b * S_LEN + kt * BN) * DK;
    short* out = (short*)(ws + (size_t)bid * TILE_B);
#pragma unroll
    for (int it = 0; it < 4; ++it) {
      int o = it * 256 + tid;
      int r = o >> 4, cix = o & 15;
      const float* src = kb + r * DK + cix * 8;
      float4 x = *(const float4*)src;
      float4 y = *(const float4*)(src + 4);
      s16x8 f;
      f[0] = f2bf(x.x); f[1] = f2bf(x.y); f[2] = f2bf(x.z); f[3] = f2bf(x.w);
      f[4] = f2bf(y.x); f[5] = f2bf(y.y); f[6] = f2bf(y.z); f[7] = f2bf(y.w);
      int pos = r * 16 + (cix ^ (r & 7));
      *(s16x8*)(out + pos * 8) = f;
    }
  } else {  // V transpose via LDS: vb = b*32 + kt
    const int vb = bid - 512;
    const float* vbase = V + (size_t)((vb >> 5) * S_LEN + (vb & 31) * BN) * DV;
    short* out = (short*)(ws + VWS_OFF + (size_t)vb * TILE_B);
#pragma unroll
    for (int i = 0; i < 8; ++i) {
      int idx = i * 256 + tid;        // float4 index, 2048 total
      int r = idx >> 5, c4 = idx & 31;
      float4 x = *(const float4*)(vbase + r * DV + c4 * 4);
      unsigned lo = ((unsigned)(unsigned short)f2bf(x.y) << 16) |
                    (unsigned short)f2bf(x.x);
      unsigned hi = ((unsigned)(unsigned short)f2bf(x.w) << 16) |
                    (unsigned short)f2bf(x.z);
      *(unsigned*)&tlds[r * 130 + c4 * 4] = lo;
      *(unsigned*)&tlds[r * 130 + c4 * 4 + 2] = hi;
    }
    __syncthreads();
#pragma unroll
    for (int i = 0; i < 2; ++i) {
      int idx = i * 256 + tid;        // pair index, 512 total
      int dp = idx >> 3, cix = idx & 7;
      int d = dp * 2;
      s16x8 f0, f1;
#pragma unroll
      for (int j = 0; j < 8; ++j) {
        int r = cix * 8 + j;
        unsigned two = *(const unsigned*)&tlds[r * 130 + d];
        f0[j] = (short)(two & 0xFFFFu);
        f1[j] = (short)(two >> 16);
      }
      int p0 = d * 8 + (cix ^ (d & 7));
      int p1 = (d + 1) * 8 + (cix ^ ((d + 1) & 7));
      *(s16x8*)(out + p0 * 8) = f0;
      *(s16x8*)(out + p1 * 8) = f1;
    }
  }
}

// ---------------------------------------------------------------------------
// Pass 2 (wave-autonomous, 32x32 MFMA): 512 blocks x 4 waves; wave =
// (batch b, q 32-row tile qt, kv half h). NO barriers, NO LDS, P stays in
// registers via swapped QK^T + cvt_pk_bf16 + v_permlane32_swap (lane l<->l+32
// exchange is exactly the kv redistribution PV's B-operand needs).
// Fixed-m softmax (m=16 base-2): halves combine by plain addition (fa_combine).
// K/V/Q fragments read directly from the swizzled ws / global (L2-resident;
// XOR folds into per-lane step-invariant offsets). K prefetched right after
// QK^T consumes it, V right after PV - latency hides under same-step compute.
// Layouts (32x32x16 bf16): A: i=l&31, k=(l>>5)*8+e. B: j=l&31, k=(l>>5)*8+e.
// C/D: col=l&31, row=(r&3)+8*(r>>2)+4*(l>>5)   [m74/m101 verified].
// Mapping: x=bid&7 (XCD), b=x+8*(j&1); blocks bid,bid+256 share a CU with
// complementary qg (sum=15) -> balanced ~130 steps/CU; heavy-first dispatch.
// ---------------------------------------------------------------------------
__global__ __launch_bounds__(256, 2)
void fa_main_wave(const float* __restrict__ Q, char* __restrict__ ws,
                  float* __restrict__ Out) {
  const int bid = blockIdx.x;           // [0,512)
  const int x = bid & 7, j = bid >> 3;  // j in [0,64)
  const int b = x + 8 * (j & 1);
  const int w = j >> 1;                 // [0,32)
  const int qg = (w < 16) ? (15 - (w >> 1)) : ((w - 16) >> 1);
  const int h  = w & 1;

  const int tid = threadIdx.x;
  const int wv = tid >> 6, ln = tid & 63;
  const int lq = ln & 31, lh = ln >> 5;
  const int qt = qg * 4 + wv;           // q 32-tile in [0,64)
  const int q0w = qt * 32;
  const int s3 = lq & 7, t3 = s3 & 3, hb = s3 >> 2;
  const float scale2 = 0.12751741f;     // log2(e)/sqrt(128), folded into Q

  const int nkv = qt + 1;               // causal 32-kv tiles for this q tile
  const int lo  = h ? ((nkv + 1) >> 1) : 0;
  const int hi2 = h ? nkv : ((nkv + 1) >> 1);

  // Q frags (B-operand): lane holds Q[q0w+lq][kc*16 + lh*8 + e] * scale2
  bf16x8 qf[8];
  {
    const float* qrow = Q + (size_t)(b * S_LEN + q0w + lq) * DK + lh * 8;
#pragma unroll
    for (int kc = 0; kc < 8; ++kc) {
      float4 xv = *(const float4*)(qrow + kc * 16);
      float4 yv = *(const float4*)(qrow + kc * 16 + 4);
      s16x8 f;
      f[0] = f2bf(xv.x * scale2); f[1] = f2bf(xv.y * scale2);
      f[2] = f2bf(xv.z * scale2); f[3] = f2bf(xv.w * scale2);
      f[4] = f2bf(yv.x * scale2); f[5] = f2bf(yv.y * scale2);
      f[6] = f2bf(yv.z * scale2); f[7] = f2bf(yv.w * scale2);
      qf[kc] = __builtin_bit_cast(bf16x8, f);
    }
  }

  // step-invariant byte offsets into the ws tiles (XOR folded)
  int koff[8];
#pragma unroll
  for (int kc = 0; kc < 8; ++kc)
    koff[kc] = lq * 256 + (((kc * 2 + lh) ^ s3) << 4);
  int voffb[4][2];
#pragma unroll
  for (int dt = 0; dt < 4; ++dt)
#pragma unroll
    for (int kvs = 0; kvs < 2; ++kvs)
      voffb[dt][kvs] = (dt * 32 + lq) * 128 + (((kvs * 2 + lh) ^ t3) << 4);

  const char* kbase = ws + (size_t)(b * NT) * TILE_B;
  const char* vbase = ws + VWS_OFF + (size_t)(b * NT) * TILE_B;

  f32x16 oacc[4];
#pragma unroll
  for (int dt = 0; dt < 4; ++dt)
#pragma unroll
    for (int r = 0; r < 16; ++r) oacc[dt][r] = 0.f;
  float lsum = 0.f;

  bf16x8 kf[8], vf[4][2];
  if (lo < hi2) {
    {
      const char* kp = kbase + (size_t)(lo >> 1) * TILE_B + (lo & 1) * 8192;
#pragma unroll
      for (int kc = 0; kc < 8; ++kc) kf[kc] = gload8v(kp + koff[kc]);
      const char* vp = vbase + (size_t)(lo >> 1) * TILE_B + (((lo & 1) ^ hb) << 6);
#pragma unroll
      for (int dt = 0; dt < 4; ++dt)
#pragma unroll
        for (int kvs = 0; kvs < 2; ++kvs) vf[dt][kvs] = gload8v(vp + voffb[dt][kvs]);
    }
    for (int s = lo; s < hi2; ++s) {
      // S^T = K Q^T : lane holds S^T[kv=crow(r,lh)][q=lq] (pre-scaled, base-2)
      f32x16 st;
#pragma unroll
      for (int r = 0; r < 16; ++r) st[r] = 0.f;
      __builtin_amdgcn_s_setprio(1);
#pragma unroll
      for (int kc = 0; kc < 8; ++kc)
        st = __builtin_amdgcn_mfma_f32_32x32x16_bf16(kf[kc], qf[kc], st, 0, 0, 0);
      __builtin_amdgcn_s_setprio(0);
      // prefetch next K into same regs (issued after MFMAs consumed kf)
      if (s + 1 < hi2) {
        const char* kp = kbase + (size_t)((s + 1) >> 1) * TILE_B + ((s + 1) & 1) * 8192;
#pragma unroll
        for (int kc = 0; kc < 8; ++kc) kf[kc] = gload8v(kp + koff[kc]);
      }
      if (s == qt) {  // causal mask, diagonal tile only
#pragma unroll
        for (int r = 0; r < 16; ++r)
          if (((r & 3) + 8 * (r >> 2) + 4 * lh) > lq) st[r] = -1e30f;
      }
      // fixed-m softmax: P = 2^(st-16); m cancels in O = acc/l exactly
      float p[16];
#pragma unroll
      for (int r = 0; r < 16; ++r) {
        p[r] = __builtin_amdgcn_exp2f(st[r] - 16.0f);
        lsum += p[r];
      }
      // pack P^T into PV B-operand frags: kv = kvs*16 + lh*8 + e at q=lq
      unsigned a0 = cvtpk(p[0], p[1]), b0 = cvtpk(p[4], p[5]);
      unsigned a1 = cvtpk(p[2], p[3]), b1 = cvtpk(p[6], p[7]);
      plswap(a0, b0); plswap(a1, b1);
      u32x4 w0; w0[0] = a0; w0[1] = a1; w0[2] = b0; w0[3] = b1;
      bf16x8 pa0 = __builtin_bit_cast(bf16x8, w0);
      unsigned a2 = cvtpk(p[8], p[9]),  b2 = cvtpk(p[12], p[13]);
      unsigned a3 = cvtpk(p[10], p[11]), b3 = cvtpk(p[14], p[15]);
      plswap(a2, b2); plswap(a3, b3);
      u32x4 w1; w1[0] = a2; w1[1] = a3; w1[2] = b2; w1[3] = b3;
      bf16x8 pa1 = __builtin_bit_cast(bf16x8, w1);
      // O^T += V^T P^T : lane holds O^T[d=dt*32+crow(r,lh)][q=lq]
      __builtin_amdgcn_s_setprio(1);
#pragma unroll
      for (int dt = 0; dt < 4; ++dt)
        oacc[dt] = __builtin_amdgcn_mfma_f32_32x32x16_bf16(vf[dt][0], pa0, oacc[dt], 0, 0, 0);
#pragma unroll
      for (int dt = 0; dt < 4; ++dt)
        oacc[dt] = __builtin_amdgcn_mfma_f32_32x32x16_bf16(vf[dt][1], pa1, oacc[dt], 0, 0, 0);
      __builtin_amdgcn_s_setprio(0);
      // prefetch next V (issued after PV consumed vf)
      if (s + 1 < hi2) {
        const char* vp = vbase + (size_t)((s + 1) >> 1) * TILE_B + ((((s + 1) & 1) ^ hb) << 6);
#pragma unroll
        for (int dt = 0; dt < 4; ++dt)
#pragma unroll
          for (int kvs = 0; kvs < 2; ++kvs) vf[dt][kvs] = gload8v(vp + voffb[dt][kvs]);
      }
    }
  }

  // epilogue: store UNNORMALIZED partial acc + l; combine kernel finishes.
  lsum += __shfl_xor(lsum, 32);  // lanes l and l+32 hold same q
  float* obase = h ? (float*)(ws + PART_OFF) : Out;
  float* lb = (float*)(ws + (h ? L1_OFF : L0_OFF)) + (size_t)b * S_LEN;
  if (lh == 0) lb[q0w + lq] = lsum;
  float* ob = obase + (size_t)(b * S_LEN + q0w + lq) * DV;
#pragma unroll
  for (int dt = 0; dt < 4; ++dt)
#pragma unroll
    for (int g = 0; g < 4; ++g) {
      f32x4 v = {oacc[dt][g * 4 + 0], oacc[dt][g * 4 + 1],
                 oacc[dt][g * 4 + 2], oacc[dt][g * 4 + 3]};
      *(f32x4*)(ob + dt * 32 + g * 8 + 4 * lh) = v;
    }
}

// Combine: Out = (Out + P1) / (l0 + l1). 2048 blocks x 256 threads x 8 floats.
__global__ __launch_bounds__(256)
void fa_combine(float* __restrict__ Out, const char* __restrict__ ws) {
  const float* P1 = (const float*)(ws + PART_OFF);
  const float* L0 = (const float*)(ws + L0_OFF);
  const float* L1 = (const float*)(ws + L1_OFF);
  const int base = (blockIdx.x * 256 + threadIdx.x) * 8;
  const int q = base >> 7;  // global row in [0, 16*2048)
  float inv = 1.0f / (L0[q] + L1[q]);
  f32x4 a0 = *(const f32x4*)(Out + base);
  f32x4 a1 = *(const f32x4*)(P1 + base);
  f32x4 b0 = *(const f32x4*)(Out + base + 4);
  f32x4 b1 = *(const f32x4*)(P1 + base + 4);
  *(f32x4*)(Out + base)     = (a0 + a1) * inv;
  *(f32x4*)(Out + base + 4) = (b0 + b1) * inv;
}

// ---------------------------------------------------------------------------
// Mid-tier (ws fits KV only): R3's verified ping-pong kernel, 512 blocks.
// ---------------------------------------------------------------------------
__global__ __launch_bounds__(256, 2)
void fa_main_pair(const float* __restrict__ Q, const char* __restrict__ ws,
                  float* __restrict__ Out) {
  __shared__ __align__(16) short lds_p0[64 * LDP];
  __shared__ __align__(16) short lds_p1[64 * LDP];
  __shared__ float lds_l[4][64];

  const int bid = blockIdx.x;
  const int x = bid & 7, j = bid >> 3;
  int b, t;
  if (j < 32) { b = x + 8 * (j & 1); t = 16 + (j >> 1); }
  else        { int jj = j - 32; b = x + 8 * (jj & 1); t = 15 - (jj >> 1); }
  const int q0  = t * BM;
  const int tid = threadIdx.x;
  const int wv  = tid >> 6, ln = tid & 63;
  const int c   = ln & 15, qd = ln >> 4;
  const int s3  = c & 7;
  const float scale2 = 0.12751741f;

  bf16x8 qf[4][4];
#pragma unroll
  for (int qt = 0; qt < 4; ++qt) {
    const float* qrow = Q + (size_t)(b * S_LEN + q0 + qt * 16 + c) * DK + qd * 8;
#pragma unroll
    for (int ks = 0; ks < 4; ++ks) {
      float4 xv = *(const float4*)(qrow + ks * 32);
      float4 yv = *(const float4*)(qrow + ks * 32 + 4);
      s16x8 f;
      f[0] = f2bf(xv.x * scale2); f[1] = f2bf(xv.y * scale2);
      f[2] = f2bf(xv.z * scale2); f[3] = f2bf(xv.w * scale2);
      f[4] = f2bf(yv.x * scale2); f[5] = f2bf(yv.y * scale2);
      f[6] = f2bf(yv.z * scale2); f[7] = f2bf(yv.w * scale2);
      qf[qt][ks] = __builtin_bit_cast(bf16x8, f);
    }
  }
  int kgo[4], vgo[2][2];
#pragma unroll
  for (int ks = 0; ks < 4; ++ks)
    kgo[ks] = ((wv * 16 + c) * 16 + ((qd + 4 * ks) ^ s3)) * 16;
#pragma unroll
  for (int dt = 0; dt < 2; ++dt)
#pragma unroll
    for (int kvs = 0; kvs < 2; ++kvs)
      vgo[dt][kvs] = ((wv * 32 + dt * 16 + c) * 8 + ((qd + 4 * kvs) ^ s3)) * 16;

  const char* kbase = ws + (size_t)(b * NT) * TILE_B;
  const char* vbase = ws + VWS_OFF + (size_t)(b * NT) * TILE_B;

  f32x4 oacc[2][4];
#pragma unroll
  for (int dt = 0; dt < 2; ++dt)
#pragma unroll
    for (int qt = 0; qt < 4; ++qt) oacc[dt][qt] = f32x4{0.f, 0.f, 0.f, 0.f};
  float l4[4] = {0.f, 0.f, 0.f, 0.f};
  f32x4 st[4];

  auto loadK = [&](bf16x8 (&dst)[4], int kt_) {
    const char* kb_ = kbase + (size_t)kt_ * TILE_B;
#pragma unroll
    for (int ks = 0; ks < 4; ++ks) dst[ks] = gload8v(kb_ + kgo[ks]);
  };
  auto loadV = [&](bf16x8 (&dst)[2][2], int kt_) {
    const char* vb_ = vbase + (size_t)kt_ * TILE_B;
#pragma unroll
    for (int dt = 0; dt < 2; ++dt)
#pragma unroll
      for (int kvs = 0; kvs < 2; ++kvs) dst[dt][kvs] = gload8v(vb_ + vgo[dt][kvs]);
  };
  auto qk = [&](bf16x8 (&kfr)[4]) {
    __builtin_amdgcn_s_setprio(1);
#pragma unroll
    for (int qt = 0; qt < 4; ++qt) {
      f32x4 acc = f32x4{0.f, 0.f, 0.f, 0.f};
#pragma unroll
      for (int ks = 0; ks < 4; ++ks)
        acc = __builtin_amdgcn_mfma_f32_16x16x32_bf16(kfr[ks], qf[qt][ks], acc, 0, 0, 0);
      st[qt] = acc;
    }
    __builtin_amdgcn_s_setprio(0);
  };
  auto smax = [&](short* pbuf, bool mask) {
    if (mask) {
#pragma unroll
      for (int qt = 0; qt < 4; ++qt)
#pragma unroll
        for (int r = 0; r < 4; ++r)
          if (wv * 16 + qd * 4 + r > qt * 16 + c) st[qt][r] = -1e30f;
    }
#pragma unroll
    for (int qt = 0; qt < 4; ++qt) {
      float p0 = __builtin_amdgcn_exp2f(st[qt][0] - 16.0f);
      float p1 = __builtin_amdgcn_exp2f(st[qt][1] - 16.0f);
      float p2 = __builtin_amdgcn_exp2f(st[qt][2] - 16.0f);
      float p3 = __builtin_amdgcn_exp2f(st[qt][3] - 16.0f);
      l4[qt] += (p0 + p1) + (p2 + p3);
      uint2 w; w.x = cvtpk(p0, p1); w.y = cvtpk(p2, p3);
      *(uint2*)&pbuf[(qt * 16 + c) * LDP + wv * 16 + qd * 4] = w;
    }
  };
  auto pv = [&](bf16x8 (&vfr)[2][2], const short* pbuf) {
#pragma unroll
    for (int kvs = 0; kvs < 2; ++kvs) {
      bf16x8 pf[4];
#pragma unroll
      for (int qt = 0; qt < 4; ++qt)
        pf[qt] = lds8(&pbuf[(qt * 16 + c) * LDP + kvs * 32 + qd * 8]);
      __builtin_amdgcn_s_setprio(1);
#pragma unroll
      for (int dt = 0; dt < 2; ++dt)
#pragma unroll
        for (int qt = 0; qt < 4; ++qt)
          oacc[dt][qt] = __builtin_amdgcn_mfma_f32_16x16x32_bf16(
              vfr[dt][kvs], pf[qt], oacc[dt][qt], 0, 0, 0);
      __builtin_amdgcn_s_setprio(0);
    }
  };
  auto bar = [&]() {
    asm volatile("s_waitcnt lgkmcnt(0)" ::: "memory");
    __builtin_amdgcn_s_barrier();
    asm volatile("" ::: "memory");
  };

  bf16x8 kf0[4], kf1[4], vf0[2][2], vf1[2][2];
  loadK(kf0, 0); loadV(vf0, 0);
  if (t >= 1) { loadK(kf1, 1); loadV(vf1, 1); }
  qk(kf0);
  smax(lds_p0, t == 0);
  bar();
  int kt = 0;
  while (kt + 1 <= t) {
    qk(kf1);
    if (kt + 2 <= t) loadK(kf0, kt + 2);
    pv(vf0, lds_p0);
    if (kt + 2 <= t) loadV(vf0, kt + 2);
    smax(lds_p1, kt + 1 == t);
    bar();
    ++kt;
    if (kt + 1 > t) break;
    qk(kf0);
    if (kt + 2 <= t) loadK(kf1, kt + 2);
    pv(vf1, lds_p1);
    if (kt + 2 <= t) loadV(vf1, kt + 2);
    smax(lds_p0, kt + 1 == t);
    bar();
    ++kt;
  }
  if (t & 1) pv(vf1, lds_p1);
  else       pv(vf0, lds_p0);

#pragma unroll
  for (int qt = 0; qt < 4; ++qt) {
    l4[qt] += __shfl_xor(l4[qt], 16);
    l4[qt] += __shfl_xor(l4[qt], 32);
  }
  if (qd == 0) {
#pragma unroll
    for (int qt = 0; qt < 4; ++qt) lds_l[wv][qt * 16 + c] = l4[qt];
  }
  __syncthreads();
  float lt[4];
#pragma unroll
  for (int qt = 0; qt < 4; ++qt)
    lt[qt] = lds_l[0][qt * 16 + c] + lds_l[1][qt * 16 + c] +
             lds_l[2][qt * 16 + c] + lds_l[3][qt * 16 + c];
#pragma unroll
  for (int qt = 0; qt < 4; ++qt) {
    float inv = 1.0f / lt[qt];
    float* ob = Out + (size_t)(b * S_LEN + q0 + qt * 16 + c) * DV + wv * 32;
#pragma unroll
    for (int dt = 0; dt < 2; ++dt) {
      f32x4 v = oacc[dt][qt] * inv;
      *(f32x4*)(ob + dt * 16 + qd * 4) = v;
    }
  }
}

// ---------------------------------------------------------------------------
// Fallback (ws too small): verified single-pass kernel, in-kernel convert.
// ---------------------------------------------------------------------------
__global__ __launch_bounds__(256)
void fa_fallback(const float* __restrict__ Q, const float* __restrict__ K,
                 const float* __restrict__ V, float* __restrict__ Out) {
  __shared__ __align__(16) short lds_k[BN * 136];
  __shared__ __align__(16) short lds_vt[DV * 72];
  __shared__ __align__(16) short lds_p[4 * 16 * LDP];

  const int bid = blockIdx.x;
  const int b = bid >> 5, t = bid & 31;
  const int q0 = t * BM;
  const int tid = threadIdx.x;
  const int wv = tid >> 6, ln = tid & 63;
  const int c = ln & 15, qd = ln >> 4;
  const float scale2 = 0.12751741f;
  const int qg = q0 + wv * 16 + c;

  bf16x8 qf[4];
  {
    const float* qrow = Q + (size_t)(b * S_LEN + qg) * DK + qd * 8;
#pragma unroll
    for (int t4 = 0; t4 < 4; ++t4) {
      float4 x = *(const float4*)(qrow + t4 * 32);
      float4 y = *(const float4*)(qrow + t4 * 32 + 4);
      s16x8 f;
      f[0] = f2bf(x.x * scale2); f[1] = f2bf(x.y * scale2);
      f[2] = f2bf(x.z * scale2); f[3] = f2bf(x.w * scale2);
      f[4] = f2bf(y.x * scale2); f[5] = f2bf(y.y * scale2);
      f[6] = f2bf(y.z * scale2); f[7] = f2bf(y.w * scale2);
      qf[t4] = __builtin_bit_cast(bf16x8, f);
    }
  }
  f32x4 oacc[8];
#pragma unroll
  for (int i = 0; i < 8; ++i) oacc[i] = f32x4{0.f, 0.f, 0.f, 0.f};
  float m_i = -1e30f, l_i = 0.f;
  const float* kbb = K + (size_t)b * S_LEN * DK;
  const float* vbb = V + (size_t)b * S_LEN * DV;
  short* pb = &lds_p[wv * 16 * LDP];

  for (int kt = 0; kt <= t; ++kt) {
    const int kv0 = kt * BN;
    __syncthreads();
    {
      const float* kb = kbb + (size_t)kv0 * DK;
#pragma unroll
      for (int it = 0; it < 8; ++it) {
        int flat = it * 256 + tid;
        int r = flat >> 5, d4 = flat & 31;
        float4 x = *(const float4*)(kb + r * DK + d4 * 4);
        s16x4 s;
        s[0] = f2bf(x.x); s[1] = f2bf(x.y); s[2] = f2bf(x.z); s[3] = f2bf(x.w);
        *(s16x4*)&lds_k[r * 136 + d4 * 4] = s;
      }
      const float* vb = vbb + (size_t)kv0 * DV;
#pragma unroll
      for (int it = 0; it < 8; ++it) {
        int flat = it * 256 + tid;
        int d = flat & 127, r0 = (flat >> 7) << 2;
        s16x4 s;
        s[0] = f2bf(vb[(r0 + 0) * DV + d]);
        s[1] = f2bf(vb[(r0 + 1) * DV + d]);
        s[2] = f2bf(vb[(r0 + 2) * DV + d]);
        s[3] = f2bf(vb[(r0 + 3) * DV + d]);
        *(s16x4*)&lds_vt[d * 72 + r0] = s;
      }
    }
    __syncthreads();
    f32x4 st[4];
#pragma unroll
    for (int cb = 0; cb < 4; ++cb) {
      f32x4 acc = f32x4{0.f, 0.f, 0.f, 0.f};
      const short* kr = &lds_k[(cb * 16 + c) * 136 + qd * 8];
#pragma unroll
      for (int t4 = 0; t4 < 4; ++t4)
        acc = __builtin_amdgcn_mfma_f32_16x16x32_bf16(lds8(kr + t4 * 32), qf[t4], acc, 0, 0, 0);
      st[cb] = acc;
    }
    if (kt == t) {
#pragma unroll
      for (int cb = 0; cb < 4; ++cb)
#pragma unroll
        for (int r = 0; r < 4; ++r)
          if (cb * 16 + qd * 4 + r > wv * 16 + c) st[cb][r] = -1e30f;
    }
    float tmax = -1e30f;
#pragma unroll
    for (int cb = 0; cb < 4; ++cb)
#pragma unroll
      for (int r = 0; r < 4; ++r) tmax = fmaxf(tmax, st[cb][r]);
    tmax = fmaxf(tmax, __shfl_xor(tmax, 16));
    tmax = fmaxf(tmax, __shfl_xor(tmax, 32));
    float mn = fmaxf(m_i, tmax);
    float al = __builtin_amdgcn_exp2f(m_i - mn);
    m_i = mn;
    float tsum = 0.f;
#pragma unroll
    for (int cb = 0; cb < 4; ++cb) {
      s16x4 pk;
#pragma unroll
      for (int r = 0; r < 4; ++r) {
        float p = __builtin_amdgcn_exp2f(st[cb][r] - m_i);
        tsum += p;
        pk[r] = f2bf(p);
      }
      *(s16x4*)&pb[c * LDP + cb * 16 + qd * 4] = pk;
    }
    tsum += __shfl_xor(tsum, 16);
    tsum += __shfl_xor(tsum, 32);
    l_i = l_i * al + tsum;
#pragma unroll
    for (int i = 0; i < 8; ++i)
#pragma unroll
      for (int r = 0; r < 4; ++r) oacc[i][r] *= al;
#pragma unroll
    for (int t2 = 0; t2 < 2; ++t2) {
      bf16x8 pf = lds8(&pb[c * LDP + t2 * 32 + qd * 8]);
#pragma unroll
      for (int cb2 = 0; cb2 < 8; ++cb2) {
        bf16x8 vf = lds8(&lds_vt[(cb2 * 16 + c) * 72 + t2 * 32 + qd * 8]);
        oacc[cb2] = __builtin_amdgcn_mfma_f32_16x16x32_bf16(vf, pf, oacc[cb2], 0, 0, 0);
      }
    }
  }
  float inv = 1.0f / l_i;
  float* ob = Out + (size_t)(b * S_LEN + qg) * DV;
#pragma unroll
  for (int cb2 = 0; cb2 < 8; ++cb2) {
    f32x4 v = oacc[cb2] * inv;
    *(f32x4*)(ob + cb2 * 16 + qd * 4) = v;
  }
}

extern "C" void kernel_launch(void* const* d_in, const int* in_sizes, int n_in,
                              void* d_out, int out_size, void* d_ws, size_t ws_size,
                              hipStream_t stream) {
  (void)in_sizes; (void)n_in; (void)out_size;
  const float* Q = (const float*)d_in[0];
  const float* K = (const float*)d_in[1];
  const float* V = (const float*)d_in[2];
  float* O = (float*)d_out;
  if (ws_size >= WS_NEED_SPLIT) {
    fa_convert<<<dim3(1024), dim3(256), 0, stream>>>(K, V, (char*)d_ws);
    fa_main_wave<<<dim3(512), dim3(256), 0, stream>>>(Q, (char*)d_ws, O);
    fa_combine<<<dim3(2048), dim3(256), 0, stream>>>(O, (const char*)d_ws);
  } else if (ws_size >= WS_NEED) {
    fa_convert<<<dim3(1024), dim3(256), 0, stream>>>(K, V, (char*)d_ws);
    fa_main_pair<<<dim3(512), dim3(256), 0, stream>>>(Q, (const char*)d_ws, O);
  } else {
    fa_fallback<<<dim3(512), dim3(256), 0, stream>>>(Q, K, V, O);
  }
}

// Round 7
// 128.104 us; speedup vs baseline: 2.7641x; 1.0481x over previous
//
#include <hip/hip_runtime.h>
#include <hip/hip_bf16.h>

#define S_LEN 2048
#define DK 128
#define DV 128
#define BN 64     // KV rows per ws tile (2 subtiles of 32)
#define NT 32     // KV 64-tiles per batch
#define TILE_B 16384                        // bytes per 64x128 bf16 tile
#define VWS_OFF ((size_t)16 * NT * TILE_B)  // 8.39 MB
#define WS_NEED ((size_t)2 * 16 * NT * TILE_B)
// split-KV partial buffers
#define PART_OFF WS_NEED                              // h=1 acc partial, 16.78 MB
#define PART_B   ((size_t)16 * S_LEN * DV * 4)
#define L0_OFF   (PART_OFF + PART_B)                  // l partials, 128 KB each
#define L1_OFF   (L0_OFF + (size_t)16 * S_LEN * 4)
#define WS_NEED_SPLIT (L1_OFF + (size_t)16 * S_LEN * 4)

typedef __attribute__((ext_vector_type(8))) short s16x8;
typedef __attribute__((ext_vector_type(4))) short s16x4;
typedef __attribute__((ext_vector_type(8))) __bf16 bf16x8;
typedef __attribute__((ext_vector_type(4))) float f32x4;
typedef __attribute__((ext_vector_type(16))) float f32x16;
typedef __attribute__((ext_vector_type(4))) unsigned u32x4;

__device__ __forceinline__ short f2bf(float f) {
  unsigned u = __builtin_bit_cast(unsigned, f);
  u += 0x7FFFu + ((u >> 16) & 1u);
  return (short)(u >> 16);
}
__device__ __forceinline__ bf16x8 lds8(const short* p) {
  return __builtin_bit_cast(bf16x8, *(const s16x8*)p);
}
__device__ __forceinline__ bf16x8 gload8v(const char* p) {
  return __builtin_bit_cast(bf16x8, *(const s16x8*)p);
}
// packed f32x2 -> bf16x2 (RNE): low = a, high = b
__device__ __forceinline__ unsigned cvtpk(float a, float b) {
  unsigned r;
  asm("v_cvt_pk_bf16_f32 %0, %1, %2" : "=v"(r) : "v"(a), "v"(b));
  return r;
}
// v_permlane32_swap_b32: a'[l] = l<32 ? a[l] : b[l-32];
//                        b'[l] = l<32 ? a[l+32] : b[l]
__device__ __forceinline__ void plswap(unsigned& a, unsigned& b) {
  asm volatile("s_nop 1\n\tv_permlane32_swap_b32 %0, %1" : "+v"(a), "+v"(b));
}

// ---------------------------------------------------------------------------
// Pass 1: convert K -> bf16, V -> bf16-transposed, in FRAGMENT-MAJOR order:
// per 32-kv subtile (8192 B), the 16B chunk lane ln needs for fragment f
// lives at  subtile*8192 + f*1024 + ln*16  -> every fa_main_wave frag load
// is a contiguous 128B-aligned 1KB block (8 cache lines, the minimum).
// The old XOR swizzle (an LDS-bank artifact) produced 32-line scatter per
// load - the R6-diagnosed TA/address-pipe wall.
//   K chunk (kc,ln):  ln=(lh*32+lq) -> K[kv0+lq][kc*16+lh*8 .. +8]
//   V chunk (dt,kvs,ln):            -> V^T[dt*32+lq][kv0+kvs*16+lh*8 .. +8]
// ---------------------------------------------------------------------------
__global__ __launch_bounds__(256)
void fa_convert(const float* __restrict__ K, const float* __restrict__ V,
                char* __restrict__ ws) {
  __shared__ short tlds[BN * 130];  // 16640 B, V path only
  const int bid = blockIdx.x;
  const int tid = threadIdx.x;
  if (bid < 512) {  // K: bid = b*32 + kt
    const int b = bid >> 5, kt = bid & 31;
    const float* kb = K + (size_t)(b * S_LEN + kt * BN) * DK;
    short* out = (short*)(ws + (size_t)bid * TILE_B);
#pragma unroll
    for (int it = 0; it < 4; ++it) {
      int o = it * 256 + tid;
      int r = o >> 4, cix = o & 15;          // row in [0,64), 32B col-chunk
      const float* src = kb + r * DK + cix * 8;
      float4 x = *(const float4*)src;
      float4 y = *(const float4*)(src + 4);
      s16x8 f;
      f[0] = f2bf(x.x); f[1] = f2bf(x.y); f[2] = f2bf(x.z); f[3] = f2bf(x.w);
      f[4] = f2bf(y.x); f[5] = f2bf(y.y); f[6] = f2bf(y.z); f[7] = f2bf(y.w);
      int s2 = r >> 5, lq = r & 31, kc = cix >> 1, lh = cix & 1;
      int elem = s2 * 4096 + kc * 512 + (lh * 32 + lq) * 8;
      *(s16x8*)(out + elem) = f;
    }
  } else {  // V transpose via LDS: vb = b*32 + kt
    const int vb = bid - 512;
    const float* vbase = V + (size_t)((vb >> 5) * S_LEN + (vb & 31) * BN) * DV;
    short* out = (short*)(ws + VWS_OFF + (size_t)vb * TILE_B);
#pragma unroll
    for (int i = 0; i < 8; ++i) {
      int idx = i * 256 + tid;        // float4 index, 2048 total
      int r = idx >> 5, c4 = idx & 31;
      float4 x = *(const float4*)(vbase + r * DV + c4 * 4);
      unsigned lo = ((unsigned)(unsigned short)f2bf(x.y) << 16) |
                    (unsigned short)f2bf(x.x);
      unsigned hi = ((unsigned)(unsigned short)f2bf(x.w) << 16) |
                    (unsigned short)f2bf(x.z);
      *(unsigned*)&tlds[r * 130 + c4 * 4] = lo;
      *(unsigned*)&tlds[r * 130 + c4 * 4 + 2] = hi;
    }
    __syncthreads();
#pragma unroll
    for (int i = 0; i < 2; ++i) {
      int idx = i * 256 + tid;        // pair index, 512 total
      int dp = idx >> 3, cix = idx & 7;
      int d = dp * 2;                 // even d; d and d+1 share d>>5
      s16x8 f0, f1;
#pragma unroll
      for (int j = 0; j < 8; ++j) {
        int r = cix * 8 + j;
        unsigned two = *(const unsigned*)&tlds[r * 130 + d];
        f0[j] = (short)(two & 0xFFFFu);
        f1[j] = (short)(two >> 16);
      }
      int s2 = cix >> 2, c2 = cix & 3, kvs = c2 >> 1, lh = c2 & 1;
      int dt = d >> 5, lq = d & 31;
      int ebase = s2 * 4096 + (dt * 2 + kvs) * 512 + lh * 256;
      *(s16x8*)(out + ebase + lq * 8)       = f0;
      *(s16x8*)(out + ebase + (lq + 1) * 8) = f1;
    }
  }
}

// ---------------------------------------------------------------------------
// Pass 2 (wave-autonomous, 32x32 MFMA): 512 blocks x 4 waves; wave =
// (batch b, q 32-row tile qt, kv half h). NO barriers, NO LDS, P stays in
// registers via swapped QK^T + cvt_pk_bf16 + v_permlane32_swap.
// Fixed-m softmax (m=16 base-2): halves combine by plain addition (fa_combine).
// K/V frags read directly from the FRAGMENT-MAJOR ws: each load is a
// contiguous 1KB block at  base + s*8192 + frag*1024 + ln*16  (coalesced,
// 8 cache lines - was 32 with the swizzled layout, the R6 TA wall).
// K prefetched right after QK^T consumes it, V right after PV.
// Layouts (32x32x16 bf16): A: i=l&31, k=(l>>5)*8+e. B: j=l&31, k=(l>>5)*8+e.
// C/D: col=l&31, row=(r&3)+8*(r>>2)+4*(l>>5)   [m74/m101 verified].
// Mapping: x=bid&7 (XCD), b=x+8*(j&1); blocks bid,bid+256 share a CU with
// complementary qg (sum=15) -> balanced ~130 steps/CU; heavy-first dispatch.
// ---------------------------------------------------------------------------
__global__ __launch_bounds__(256, 2)
void fa_main_wave(const float* __restrict__ Q, char* __restrict__ ws,
                  float* __restrict__ Out) {
  const int bid = blockIdx.x;           // [0,512)
  const int x = bid & 7, j = bid >> 3;  // j in [0,64)
  const int b = x + 8 * (j & 1);
  const int w = j >> 1;                 // [0,32)
  const int qg = (w < 16) ? (15 - (w >> 1)) : ((w - 16) >> 1);
  const int h  = w & 1;

  const int tid = threadIdx.x;
  const int wv = tid >> 6, ln = tid & 63;
  const int lq = ln & 31, lh = ln >> 5;
  const int qt = qg * 4 + wv;           // q 32-tile in [0,64)
  const int q0w = qt * 32;
  const int lb16 = ln * 16;             // coalesced per-lane byte offset
  const float scale2 = 0.12751741f;     // log2(e)/sqrt(128), folded into Q

  const int nkv = qt + 1;               // causal 32-kv tiles for this q tile
  const int lo  = h ? ((nkv + 1) >> 1) : 0;
  const int hi2 = h ? nkv : ((nkv + 1) >> 1);

  // Q frags (B-operand): lane holds Q[q0w+lq][kc*16 + lh*8 + e] * scale2
  bf16x8 qf[8];
  {
    const float* qrow = Q + (size_t)(b * S_LEN + q0w + lq) * DK + lh * 8;
#pragma unroll
    for (int kc = 0; kc < 8; ++kc) {
      float4 xv = *(const float4*)(qrow + kc * 16);
      float4 yv = *(const float4*)(qrow + kc * 16 + 4);
      s16x8 f;
      f[0] = f2bf(xv.x * scale2); f[1] = f2bf(xv.y * scale2);
      f[2] = f2bf(xv.z * scale2); f[3] = f2bf(xv.w * scale2);
      f[4] = f2bf(yv.x * scale2); f[5] = f2bf(yv.y * scale2);
      f[6] = f2bf(yv.z * scale2); f[7] = f2bf(yv.w * scale2);
      qf[kc] = __builtin_bit_cast(bf16x8, f);
    }
  }

  const char* kbase = ws + (size_t)(b * NT) * TILE_B;
  const char* vbase = ws + VWS_OFF + (size_t)(b * NT) * TILE_B;

  f32x16 oacc[4];
#pragma unroll
  for (int dt = 0; dt < 4; ++dt)
#pragma unroll
    for (int r = 0; r < 16; ++r) oacc[dt][r] = 0.f;
  float lsum = 0.f;

  bf16x8 kf[8], vf[4][2];
  if (lo < hi2) {
    {
      const char* kp = kbase + (size_t)lo * 8192;
#pragma unroll
      for (int kc = 0; kc < 8; ++kc) kf[kc] = gload8v(kp + kc * 1024 + lb16);
      const char* vp = vbase + (size_t)lo * 8192;
#pragma unroll
      for (int dt = 0; dt < 4; ++dt)
#pragma unroll
        for (int kvs = 0; kvs < 2; ++kvs)
          vf[dt][kvs] = gload8v(vp + (dt * 2 + kvs) * 1024 + lb16);
    }
    for (int s = lo; s < hi2; ++s) {
      // S^T = K Q^T : lane holds S^T[kv=crow(r,lh)][q=lq] (pre-scaled, base-2)
      f32x16 st;
#pragma unroll
      for (int r = 0; r < 16; ++r) st[r] = 0.f;
      __builtin_amdgcn_s_setprio(1);
#pragma unroll
      for (int kc = 0; kc < 8; ++kc)
        st = __builtin_amdgcn_mfma_f32_32x32x16_bf16(kf[kc], qf[kc], st, 0, 0, 0);
      __builtin_amdgcn_s_setprio(0);
      // prefetch next K into same regs (issued after MFMAs consumed kf)
      if (s + 1 < hi2) {
        const char* kp = kbase + (size_t)(s + 1) * 8192;
#pragma unroll
        for (int kc = 0; kc < 8; ++kc) kf[kc] = gload8v(kp + kc * 1024 + lb16);
      }
      if (s == qt) {  // causal mask, diagonal tile only
#pragma unroll
        for (int r = 0; r < 16; ++r)
          if (((r & 3) + 8 * (r >> 2) + 4 * lh) > lq) st[r] = -1e30f;
      }
      // fixed-m softmax: P = 2^(st-16); m cancels in O = acc/l exactly
      float p[16];
#pragma unroll
      for (int r = 0; r < 16; ++r) {
        p[r] = __builtin_amdgcn_exp2f(st[r] - 16.0f);
        lsum += p[r];
      }
      // pack P^T into PV B-operand frags: kv = kvs*16 + lh*8 + e at q=lq
      unsigned a0 = cvtpk(p[0], p[1]), b0 = cvtpk(p[4], p[5]);
      unsigned a1 = cvtpk(p[2], p[3]), b1 = cvtpk(p[6], p[7]);
      plswap(a0, b0); plswap(a1, b1);
      u32x4 w0; w0[0] = a0; w0[1] = a1; w0[2] = b0; w0[3] = b1;
      bf16x8 pa0 = __builtin_bit_cast(bf16x8, w0);
      unsigned a2 = cvtpk(p[8], p[9]),  b2 = cvtpk(p[12], p[13]);
      unsigned a3 = cvtpk(p[10], p[11]), b3 = cvtpk(p[14], p[15]);
      plswap(a2, b2); plswap(a3, b3);
      u32x4 w1; w1[0] = a2; w1[1] = a3; w1[2] = b2; w1[3] = b3;
      bf16x8 pa1 = __builtin_bit_cast(bf16x8, w1);
      // O^T += V^T P^T : lane holds O^T[d=dt*32+crow(r,lh)][q=lq]
      __builtin_amdgcn_s_setprio(1);
#pragma unroll
      for (int dt = 0; dt < 4; ++dt)
        oacc[dt] = __builtin_amdgcn_mfma_f32_32x32x16_bf16(vf[dt][0], pa0, oacc[dt], 0, 0, 0);
#pragma unroll
      for (int dt = 0; dt < 4; ++dt)
        oacc[dt] = __builtin_amdgcn_mfma_f32_32x32x16_bf16(vf[dt][1], pa1, oacc[dt], 0, 0, 0);
      __builtin_amdgcn_s_setprio(0);
      // prefetch next V (issued after PV consumed vf)
      if (s + 1 < hi2) {
        const char* vp = vbase + (size_t)(s + 1) * 8192;
#pragma unroll
        for (int dt = 0; dt < 4; ++dt)
#pragma unroll
          for (int kvs = 0; kvs < 2; ++kvs)
            vf[dt][kvs] = gload8v(vp + (dt * 2 + kvs) * 1024 + lb16);
      }
    }
  }

  // epilogue: store UNNORMALIZED partial acc + l; combine kernel finishes.
  lsum += __shfl_xor(lsum, 32);  // lanes l and l+32 hold same q
  float* obase = h ? (float*)(ws + PART_OFF) : Out;
  float* lb = (float*)(ws + (h ? L1_OFF : L0_OFF)) + (size_t)b * S_LEN;
  if (lh == 0) lb[q0w + lq] = lsum;
  float* ob = obase + (size_t)(b * S_LEN + q0w + lq) * DV;
#pragma unroll
  for (int dt = 0; dt < 4; ++dt)
#pragma unroll
    for (int g = 0; g < 4; ++g) {
      f32x4 v = {oacc[dt][g * 4 + 0], oacc[dt][g * 4 + 1],
                 oacc[dt][g * 4 + 2], oacc[dt][g * 4 + 3]};
      *(f32x4*)(ob + dt * 32 + g * 8 + 4 * lh) = v;
    }
}

// Combine: Out = (Out + P1) / (l0 + l1). 2048 blocks x 256 threads x 8 floats.
__global__ __launch_bounds__(256)
void fa_combine(float* __restrict__ Out, const char* __restrict__ ws) {
  const float* P1 = (const float*)(ws + PART_OFF);
  const float* L0 = (const float*)(ws + L0_OFF);
  const float* L1 = (const float*)(ws + L1_OFF);
  const int base = (blockIdx.x * 256 + threadIdx.x) * 8;
  const int q = base >> 7;  // global row in [0, 16*2048)
  float inv = 1.0f / (L0[q] + L1[q]);
  f32x4 a0 = *(const f32x4*)(Out + base);
  f32x4 a1 = *(const f32x4*)(P1 + base);
  f32x4 b0 = *(const f32x4*)(Out + base + 4);
  f32x4 b1 = *(const f32x4*)(P1 + base + 4);
  *(f32x4*)(Out + base)     = (a0 + a1) * inv;
  *(f32x4*)(Out + base + 4) = (b0 + b1) * inv;
}

// ---------------------------------------------------------------------------
// Fallback (ws too small for split buffers): verified single-pass kernel,
// in-kernel convert, self-contained (no ws layout dependence).
// ---------------------------------------------------------------------------
#define LDP 72
__global__ __launch_bounds__(256)
void fa_fallback(const float* __restrict__ Q, const float* __restrict__ K,
                 const float* __restrict__ V, float* __restrict__ Out) {
  __shared__ __align__(16) short lds_k[BN * 136];
  __shared__ __align__(16) short lds_vt[DV * 72];
  __shared__ __align__(16) short lds_p[4 * 16 * LDP];

  const int bid = blockIdx.x;
  const int b = bid >> 5, t = bid & 31;
  const int q0 = t * 64;
  const int tid = threadIdx.x;
  const int wv = tid >> 6, ln = tid & 63;
  const int c = ln & 15, qd = ln >> 4;
  const float scale2 = 0.12751741f;
  const int qg = q0 + wv * 16 + c;

  bf16x8 qf[4];
  {
    const float* qrow = Q + (size_t)(b * S_LEN + qg) * DK + qd * 8;
#pragma unroll
    for (int t4 = 0; t4 < 4; ++t4) {
      float4 x = *(const float4*)(qrow + t4 * 32);
      float4 y = *(const float4*)(qrow + t4 * 32 + 4);
      s16x8 f;
      f[0] = f2bf(x.x * scale2); f[1] = f2bf(x.y * scale2);
      f[2] = f2bf(x.z * scale2); f[3] = f2bf(x.w * scale2);
      f[4] = f2bf(y.x * scale2); f[5] = f2bf(y.y * scale2);
      f[6] = f2bf(y.z * scale2); f[7] = f2bf(y.w * scale2);
      qf[t4] = __builtin_bit_cast(bf16x8, f);
    }
  }
  f32x4 oacc[8];
#pragma unroll
  for (int i = 0; i < 8; ++i) oacc[i] = f32x4{0.f, 0.f, 0.f, 0.f};
  float m_i = -1e30f, l_i = 0.f;
  const float* kbb = K + (size_t)b * S_LEN * DK;
  const float* vbb = V + (size_t)b * S_LEN * DV;
  short* pb = &lds_p[wv * 16 * LDP];

  for (int kt = 0; kt <= t; ++kt) {
    const int kv0 = kt * BN;
    __syncthreads();
    {
      const float* kb = kbb + (size_t)kv0 * DK;
#pragma unroll
      for (int it = 0; it < 8; ++it) {
        int flat = it * 256 + tid;
        int r = flat >> 5, d4 = flat & 31;
        float4 x = *(const float4*)(kb + r * DK + d4 * 4);
        s16x4 s;
        s[0] = f2bf(x.x); s[1] = f2bf(x.y); s[2] = f2bf(x.z); s[3] = f2bf(x.w);
        *(s16x4*)&lds_k[r * 136 + d4 * 4] = s;
      }
      const float* vb = vbb + (size_t)kv0 * DV;
#pragma unroll
      for (int it = 0; it < 8; ++it) {
        int flat = it * 256 + tid;
        int d = flat & 127, r0 = (flat >> 7) << 2;
        s16x4 s;
        s[0] = f2bf(vb[(r0 + 0) * DV + d]);
        s[1] = f2bf(vb[(r0 + 1) * DV + d]);
        s[2] = f2bf(vb[(r0 + 2) * DV + d]);
        s[3] = f2bf(vb[(r0 + 3) * DV + d]);
        *(s16x4*)&lds_vt[d * 72 + r0] = s;
      }
    }
    __syncthreads();
    f32x4 st[4];
#pragma unroll
    for (int cb = 0; cb < 4; ++cb) {
      f32x4 acc = f32x4{0.f, 0.f, 0.f, 0.f};
      const short* kr = &lds_k[(cb * 16 + c) * 136 + qd * 8];
#pragma unroll
      for (int t4 = 0; t4 < 4; ++t4)
        acc = __builtin_amdgcn_mfma_f32_16x16x32_bf16(lds8(kr + t4 * 32), qf[t4], acc, 0, 0, 0);
      st[cb] = acc;
    }
    if (kt == t) {
#pragma unroll
      for (int cb = 0; cb < 4; ++cb)
#pragma unroll
        for (int r = 0; r < 4; ++r)
          if (cb * 16 + qd * 4 + r > wv * 16 + c) st[cb][r] = -1e30f;
    }
    float tmax = -1e30f;
#pragma unroll
    for (int cb = 0; cb < 4; ++cb)
#pragma unroll
      for (int r = 0; r < 4; ++r) tmax = fmaxf(tmax, st[cb][r]);
    tmax = fmaxf(tmax, __shfl_xor(tmax, 16));
    tmax = fmaxf(tmax, __shfl_xor(tmax, 32));
    float mn = fmaxf(m_i, tmax);
    float al = __builtin_amdgcn_exp2f(m_i - mn);
    m_i = mn;
    float tsum = 0.f;
#pragma unroll
    for (int cb = 0; cb < 4; ++cb) {
      s16x4 pk;
#pragma unroll
      for (int r = 0; r < 4; ++r) {
        float p = __builtin_amdgcn_exp2f(st[cb][r] - m_i);
        tsum += p;
        pk[r] = f2bf(p);
      }
      *(s16x4*)&pb[c * LDP + cb * 16 + qd * 4] = pk;
    }
    tsum += __shfl_xor(tsum, 16);
    tsum += __shfl_xor(tsum, 32);
    l_i = l_i * al + tsum;
#pragma unroll
    for (int i = 0; i < 8; ++i)
#pragma unroll
      for (int r = 0; r < 4; ++r) oacc[i][r] *= al;
#pragma unroll
    for (int t2 = 0; t2 < 2; ++t2) {
      bf16x8 pf = lds8(&pb[c * LDP + t2 * 32 + qd * 8]);
#pragma unroll
      for (int cb2 = 0; cb2 < 8; ++cb2) {
        bf16x8 vf = lds8(&lds_vt[(cb2 * 16 + c) * 72 + t2 * 32 + qd * 8]);
        oacc[cb2] = __builtin_amdgcn_mfma_f32_16x16x32_bf16(vf, pf, oacc[cb2], 0, 0, 0);
      }
    }
  }
  float inv = 1.0f / l_i;
  float* ob = Out + (size_t)(b * S_LEN + qg) * DV;
#pragma unroll
  for (int cb2 = 0; cb2 < 8; ++cb2) {
    f32x4 v = oacc[cb2] * inv;
    *(f32x4*)(ob + cb2 * 16 + qd * 4) = v;
  }
}

extern "C" void kernel_launch(void* const* d_in, const int* in_sizes, int n_in,
                              void* d_out, int out_size, void* d_ws, size_t ws_size,
                              hipStream_t stream) {
  (void)in_sizes; (void)n_in; (void)out_size;
  const float* Q = (const float*)d_in[0];
  const float* K = (const float*)d_in[1];
  const float* V = (const float*)d_in[2];
  float* O = (float*)d_out;
  if (ws_size >= WS_NEED_SPLIT) {
    fa_convert<<<dim3(1024), dim3(256), 0, stream>>>(K, V, (char*)d_ws);
    fa_main_wave<<<dim3(512), dim3(256), 0, stream>>>(Q, (char*)d_ws, O);
    fa_combine<<<dim3(2048), dim3(256), 0, stream>>>(O, (const char*)d_ws);
  } else {
    fa_fallback<<<dim3(512), dim3(256), 0, stream>>>(Q, K, V, O);
  }
}